// Round 16
// baseline (250.850 us; speedup 1.0000x reference)
//
#include <hip/hip_runtime.h>
#include <math.h>

#define B_ 2
#define SEQ_ 4096
#define ST_ 128
#define T_ 4352
#define DIN_ 1024
#define NW 16
#define LMAX 3328
#define LPAD 3336
#define NSLICE 272
#define SLPAD 273
#define NROW 8704

typedef _Float16 f16;
typedef __attribute__((ext_vector_type(8))) _Float16 f16x8;
typedef __attribute__((ext_vector_type(4))) float f32x4;

// ---- new-path ws byte offsets ----
#define OB_WH  0
#define OB_WL  786432
#define OB_QH  1572864
#define OB_QL  2686976
#define OB_KH  3801088
#define OB_KL  4915200
#define OB_VT  6029312
#define OB_CPT 7143424
#define OB_SS  7569408
#define OB_XH  17039360
#define OB_XL  34865152
#define NEED_NEW 52690944ull

// ---- old-path ws float offsets ----
#define WT4_OFF 0
#define Q_OFF   393216
#define KT_OFF  950272
#define V_OFF   1507328

__device__ __forceinline__ int wuid() {
  return __builtin_amdgcn_readfirstlane((int)(threadIdx.x >> 6));
}

template<int CTRL, int RM>
__device__ __forceinline__ float dppadd(float x) {
  int y = __builtin_amdgcn_update_dpp(0, __float_as_int(x), CTRL, RM, 0xf, true);
  return x + __int_as_float(y);
}
__device__ __forceinline__ float wave_iscan(float x) {
  x = dppadd<0x111, 0xf>(x);
  x = dppadd<0x112, 0xf>(x);
  x = dppadd<0x114, 0xf>(x);
  x = dppadd<0x118, 0xf>(x);
  x = dppadd<0x142, 0xa>(x);
  x = dppadd<0x143, 0xc>(x);
  return x;
}
__device__ __forceinline__ float p16scan(float x) {
  x = dppadd<0x111, 0xf>(x);
  x = dppadd<0x112, 0xf>(x);
  x = dppadd<0x114, 0xf>(x);
  x = dppadd<0x118, 0xf>(x);
  return x;
}
__device__ __forceinline__ float swz15(float x) {
  return __int_as_float(__builtin_amdgcn_ds_swizzle(__float_as_int(x), 0x1F0));
}

// ---------------- W split -> fp16 hi/lo ----------------
__global__ __launch_bounds__(256) void wsplit_kernel(
    const float* __restrict__ Wq,  const float* __restrict__ Wk,
    const float* __restrict__ Wv,  const float* __restrict__ Wqs,
    const float* __restrict__ Wks, const float* __restrict__ Wvs,
    f16* __restrict__ wh, f16* __restrict__ wl) {
  const int m = blockIdx.y;
  const float* src = (m==0)?Wq:(m==1)?Wqs:(m==2)?Wk:(m==3)?Wks:(m==4)?Wv:Wvs;
  const int g0 = (int)blockIdx.x * 4096 + (int)threadIdx.x * 16;
  const float4* s4 = reinterpret_cast<const float4*>(src + g0);
  float4 v0 = s4[0], v1 = s4[1], v2 = s4[2], v3 = s4[3];
  f16x8 h0, h1, l0, l1;
  h0[0]=(f16)v0.x; h0[1]=(f16)v0.y; h0[2]=(f16)v0.z; h0[3]=(f16)v0.w;
  h0[4]=(f16)v1.x; h0[5]=(f16)v1.y; h0[6]=(f16)v1.z; h0[7]=(f16)v1.w;
  h1[0]=(f16)v2.x; h1[1]=(f16)v2.y; h1[2]=(f16)v2.z; h1[3]=(f16)v2.w;
  h1[4]=(f16)v3.x; h1[5]=(f16)v3.y; h1[6]=(f16)v3.z; h1[7]=(f16)v3.w;
  l0[0]=(f16)(v0.x-(float)h0[0]); l0[1]=(f16)(v0.y-(float)h0[1]);
  l0[2]=(f16)(v0.z-(float)h0[2]); l0[3]=(f16)(v0.w-(float)h0[3]);
  l0[4]=(f16)(v1.x-(float)h0[4]); l0[5]=(f16)(v1.y-(float)h0[5]);
  l0[6]=(f16)(v1.z-(float)h0[6]); l0[7]=(f16)(v1.w-(float)h0[7]);
  l1[0]=(f16)(v2.x-(float)h1[0]); l1[1]=(f16)(v2.y-(float)h1[1]);
  l1[2]=(f16)(v2.z-(float)h1[2]); l1[3]=(f16)(v2.w-(float)h1[3]);
  l1[4]=(f16)(v3.x-(float)h1[4]); l1[5]=(f16)(v3.y-(float)h1[5]);
  l1[6]=(f16)(v3.z-(float)h1[6]); l1[7]=(f16)(v3.w-(float)h1[7]);
  const size_t o = (size_t)m * 65536 + g0;
  *reinterpret_cast<f16x8*>(wh + o) = h0;
  *reinterpret_cast<f16x8*>(wh + o + 8) = h1;
  *reinterpret_cast<f16x8*>(wl + o) = l0;
  *reinterpret_cast<f16x8*>(wl + o + 8) = l1;
}

// ---------------- x split -> fp16 hi/lo ----------------
__global__ __launch_bounds__(256) void xsplit_kernel(
    const float* __restrict__ x, f16* __restrict__ xh, f16* __restrict__ xl) {
  const size_t g0 = ((size_t)blockIdx.x * 256 + threadIdx.x) * 16;
  const float4* s4 = reinterpret_cast<const float4*>(x + g0);
  float4 v0 = s4[0], v1 = s4[1], v2 = s4[2], v3 = s4[3];
  f16x8 h0, h1, l0, l1;
  h0[0]=(f16)v0.x; h0[1]=(f16)v0.y; h0[2]=(f16)v0.z; h0[3]=(f16)v0.w;
  h0[4]=(f16)v1.x; h0[5]=(f16)v1.y; h0[6]=(f16)v1.z; h0[7]=(f16)v1.w;
  h1[0]=(f16)v2.x; h1[1]=(f16)v2.y; h1[2]=(f16)v2.z; h1[3]=(f16)v2.w;
  h1[4]=(f16)v3.x; h1[5]=(f16)v3.y; h1[6]=(f16)v3.z; h1[7]=(f16)v3.w;
  l0[0]=(f16)(v0.x-(float)h0[0]); l0[1]=(f16)(v0.y-(float)h0[1]);
  l0[2]=(f16)(v0.z-(float)h0[2]); l0[3]=(f16)(v0.w-(float)h0[3]);
  l0[4]=(f16)(v1.x-(float)h0[4]); l0[5]=(f16)(v1.y-(float)h0[5]);
  l0[6]=(f16)(v1.z-(float)h0[6]); l0[7]=(f16)(v1.w-(float)h0[7]);
  l1[0]=(f16)(v2.x-(float)h1[0]); l1[1]=(f16)(v2.y-(float)h1[1]);
  l1[2]=(f16)(v2.z-(float)h1[2]); l1[3]=(f16)(v2.w-(float)h1[3]);
  l1[4]=(f16)(v3.x-(float)h1[4]); l1[5]=(f16)(v3.y-(float)h1[5]);
  l1[6]=(f16)(v3.z-(float)h1[6]); l1[7]=(f16)(v3.w-(float)h1[7]);
  *reinterpret_cast<f16x8*>(xh + g0) = h0;
  *reinterpret_cast<f16x8*>(xh + g0 + 8) = h1;
  *reinterpret_cast<f16x8*>(xl + g0) = l0;
  *reinterpret_cast<f16x8*>(xl + g0 + 8) = l1;
}

// ---------------- cope transpose -> fp16 ----------------
__global__ __launch_bounds__(256) void copet_kernel(
    const float* __restrict__ cope, f16* __restrict__ copeT) {
  __shared__ float t2[64][65];
  const int l0 = blockIdx.x << 6;
  const int tid = (int)threadIdx.x;
  #pragma unroll
  for (int p = 0; p < 16; ++p) {
    int d = (p << 2) + (tid >> 6), c = tid & 63;
    t2[d][c] = cope[(size_t)d * T_ + l0 + c];
  }
  __syncthreads();
  #pragma unroll
  for (int p = 0; p < 16; ++p) {
    int l = (p << 2) + (tid >> 6), d = tid & 63;
    copeT[(size_t)(l0 + l) * 64 + d] = (f16)t2[d][l];
  }
}

// ======== projM macros (3-pass kept; 8-wave K-split) ========
#define PM_MFMA(ACC, WHP, WLP) { \
  f16x8 bh_ = *reinterpret_cast<const f16x8*>((WHP) + (st << 5)); \
  f16x8 bl_ = *reinterpret_cast<const f16x8*>((WLP) + (st << 5)); \
  ACC = __builtin_amdgcn_mfma_f32_16x16x32_f16(xh_, bh_, ACC, 0, 0, 0); \
  ACC = __builtin_amdgcn_mfma_f32_16x16x32_f16(xl_, bh_, ACC, 0, 0, 0); \
  ACC = __builtin_amdgcn_mfma_f32_16x16x32_f16(xh_, bl_, ACC, 0, 0, 0); }

#define PM_RED(ACC, P) { \
  float s0_ = ACC[0]*ACC[0], s1_ = ACC[1]*ACC[1], s2_ = ACC[2]*ACC[2], s3_ = ACC[3]*ACC[3]; \
  s0_ += __shfl_xor(s0_, 1, 64); s1_ += __shfl_xor(s1_, 1, 64); \
  s2_ += __shfl_xor(s2_, 1, 64); s3_ += __shfl_xor(s3_, 1, 64); \
  s0_ += __shfl_xor(s0_, 2, 64); s1_ += __shfl_xor(s1_, 2, 64); \
  s2_ += __shfl_xor(s2_, 2, 64); s3_ += __shfl_xor(s3_, 2, 64); \
  s0_ += __shfl_xor(s0_, 4, 64); s1_ += __shfl_xor(s1_, 4, 64); \
  s2_ += __shfl_xor(s2_, 4, 64); s3_ += __shfl_xor(s3_, 4, 64); \
  s0_ += __shfl_xor(s0_, 8, 64); s1_ += __shfl_xor(s1_, 8, 64); \
  s2_ += __shfl_xor(s2_, 8, 64); s3_ += __shfl_xor(s3_, 8, 64); \
  if (qlo == 0) { \
    ssq[wn][P][(qhi << 2) + 0] = s0_; ssq[wn][P][(qhi << 2) + 1] = s1_; \
    ssq[wn][P][(qhi << 2) + 2] = s2_; ssq[wn][P][(qhi << 2) + 3] = s3_; } }

#define PM_QK1(ACC, P, HH, LL, RG) { \
  float tt_ = ssq[0][P][(qhi << 2) + RG] + ssq[1][P][(qhi << 2) + RG] \
            + ssq[2][P][(qhi << 2) + RG] + ssq[3][P][(qhi << 2) + RG]; \
  float rn_ = 1.f / fmaxf(sqrtf(tt_), 1e-12f); \
  float v_ = ACC[RG] * rn_; \
  f16 h_ = (f16)v_; \
  size_t ad_ = (size_t)(bt0 + (qhi << 2) + RG) * 64 + (wn << 4) + qlo; \
  HH[ad_] = h_; LL[ad_] = (f16)(v_ - (float)h_); }

#define PM_V1(ACC, P, RG) { \
  float tt_ = ssq[0][P][(qhi << 2) + RG] + ssq[1][P][(qhi << 2) + RG] \
            + ssq[2][P][(qhi << 2) + RG] + ssq[3][P][(qhi << 2) + RG]; \
  float rn_ = 1.f / fmaxf(sqrtf(tt_), 1e-12f); \
  vt[(size_t)(b * 64 + (wn << 4) + qlo) * T_ + t0 + (qhi << 2) + RG] = (f16)(ACC[RG] * rn_); }

// ---------------- MFMA projections + l2norm (8 waves, K-split) ----------------
__global__ __launch_bounds__(512, 4) void projM_kernel(
    const f16* __restrict__ xh, const f16* __restrict__ xl,
    const f16* __restrict__ wh, const f16* __restrict__ wl,
    f16* __restrict__ qh, f16* __restrict__ ql,
    f16* __restrict__ kh, f16* __restrict__ kl,
    f16* __restrict__ vt) {
  __shared__ float ssq[4][3][16];
  __shared__ float part[4][64][12];
  const int lane = (int)threadIdx.x & 63;
  const int w = wuid();
  const int wn = w & 3;
  const int kh2 = w >> 2;
  const int qlo = lane & 15, qhi = lane >> 4;
  const int bt0 = (int)blockIdx.x << 4;
  const int b = bt0 / T_;
  const int t0 = bt0 - b * T_;
  const int spec = (t0 < ST_ || t0 >= ST_ + SEQ_) ? 1 : 0;

  const int kof = kh2 << 9;
  const f16* xhr = xh + (size_t)(bt0 + qlo) * DIN_ + kof + (qhi << 3);
  const f16* xlr = xl + (size_t)(bt0 + qlo) * DIN_ + kof + (qhi << 3);
  const size_t wrow = (size_t)((wn << 4) + qlo) * 1024 + kof + (qhi << 3);
  const f16* wq  = wh + (size_t)(0 + spec) * 65536 + wrow;
  const f16* wqL = wl + (size_t)(0 + spec) * 65536 + wrow;
  const f16* wk  = wh + (size_t)(2 + spec) * 65536 + wrow;
  const f16* wkL = wl + (size_t)(2 + spec) * 65536 + wrow;
  const f16* wv  = wh + (size_t)(4 + spec) * 65536 + wrow;
  const f16* wvL = wl + (size_t)(4 + spec) * 65536 + wrow;

  f32x4 aq = {0.f,0.f,0.f,0.f}, ak = {0.f,0.f,0.f,0.f}, av = {0.f,0.f,0.f,0.f};

  #pragma unroll 4
  for (int st = 0; st < 16; ++st) {
    f16x8 xh_ = *reinterpret_cast<const f16x8*>(xhr + (st << 5));
    f16x8 xl_ = *reinterpret_cast<const f16x8*>(xlr + (st << 5));
    PM_MFMA(aq, wq, wqL)
    PM_MFMA(ak, wk, wkL)
    PM_MFMA(av, wv, wvL)
  }

  if (w >= 4) {
    float* p = &part[w - 4][lane][0];
    p[0] = aq[0]; p[1] = aq[1]; p[2]  = aq[2]; p[3]  = aq[3];
    p[4] = ak[0]; p[5] = ak[1]; p[6]  = ak[2]; p[7]  = ak[3];
    p[8] = av[0]; p[9] = av[1]; p[10] = av[2]; p[11] = av[3];
  }
  __syncthreads();
  if (w < 4) {
    const float* p = &part[w][lane][0];
    aq[0] += p[0]; aq[1] += p[1]; aq[2] += p[2];  aq[3] += p[3];
    ak[0] += p[4]; ak[1] += p[5]; ak[2] += p[6];  ak[3] += p[7];
    av[0] += p[8]; av[1] += p[9]; av[2] += p[10]; av[3] += p[11];
    PM_RED(aq, 0) PM_RED(ak, 1) PM_RED(av, 2)
  }
  __syncthreads();
  if (w < 4) {
    PM_QK1(aq, 0, qh, ql, 0) PM_QK1(aq, 0, qh, ql, 1)
    PM_QK1(aq, 0, qh, ql, 2) PM_QK1(aq, 0, qh, ql, 3)
    PM_QK1(ak, 1, kh, kl, 0) PM_QK1(ak, 1, kh, kl, 1)
    PM_QK1(ak, 1, kh, kl, 2) PM_QK1(ak, 1, kh, kl, 3)
    PM_V1(av, 2, 0) PM_V1(av, 2, 1) PM_V1(av, 2, 2) PM_V1(av, 2, 3)
  }
}

// ======== attnE macros (single-pass QK; PX split; in-LDS ss) ========
#define QKD(SF, NF) { \
  int sg_ = swb + (NF << 4) + qlo; \
  int scl_ = sg_ < T_ ? sg_ : T_ - 1; \
  const f16* krh_ = kh + bT64 + (size_t)scl_ * 64 + (qhi << 3); \
  f16x8 bh0_ = *reinterpret_cast<const f16x8*>(krh_); \
  f16x8 bh1_ = *reinterpret_cast<const f16x8*>(krh_ + 32); \
  f32x4 a_ = {0.f, 0.f, 0.f, 0.f}; \
  a_ = __builtin_amdgcn_mfma_f32_16x16x32_f16(aqh0, bh0_, a_, 0, 0, 0); \
  a_ = __builtin_amdgcn_mfma_f32_16x16x32_f16(aqh1, bh1_, a_, 0, 0, 0); \
  SF = a_; }

// phase A: sigmoid + scan + idx + issue both li reads
#define PXA(SF, RG, SSV, LF, LC, WF) { \
  float g_ = 1.f / (1.f + __expf(-SF[RG])); \
  float in_ = p16scan(g_); \
  float pos_ = SSV - in_ + g_; \
  pos_ = pos_ < 0.f ? 0.f : (pos_ > 3326.f ? 3326.f : pos_); \
  int idx_ = (int)pos_; \
  WF = pos_ - (float)idx_; \
  const f16* lrow_ = liL + ((qhi << 2) + RG) * LPAD + idx_; \
  LF = (float)lrow_[0]; LC = (float)lrow_[1]; }

// phase B: bias + mask + exp + store
#define PXB(SF, NF, RG, LF, LC, WF) { \
  int sg_ = swb + (NF << 4) + qlo; \
  float bias_ = fmaf(WF, LC - LF, LF); \
  int tl_ = t0 + (qhi << 2) + RG; \
  bool valid_ = (sg_ <= tl_) && !((tl_ >= ST_ + SEQ_) && (sg_ < ST_)); \
  float p_ = valid_ ? __expf(fmaf(SF[RG], sc, bias_) - mrw[RG]) : 0.f; \
  lsum[RG] += p_; \
  pst[((qhi << 2) + RG) * 40 + (NF << 4) + qlo] = (f16)p_; }

#define PVF(OA, NF) { \
  int d_ = (NF << 4) + qlo; \
  const f16* vr_ = vt + (size_t)(b * 64 + d_) * T_; \
  f16x8 v0_ = *reinterpret_cast<const f16x8*>(vr_ + sv0); \
  OA = __builtin_amdgcn_mfma_f32_16x16x32_f16(pa0, v0_, OA, 0, 0, 0); }

#define OST(OA, NF) { \
  ob[w * 1024 + ((qhi << 2) + 0) * 64 + (NF << 4) + qlo] = OA[0]; \
  ob[w * 1024 + ((qhi << 2) + 1) * 64 + (NF << 4) + qlo] = OA[1]; \
  ob[w * 1024 + ((qhi << 2) + 2) * 64 + (NF << 4) + qlo] = OA[2]; \
  ob[w * 1024 + ((qhi << 2) + 3) * 64 + (NF << 4) + qlo] = OA[3]; }

// ---------------- fused attention: gscan + barrier-free causal sweep ----------------
__global__ __launch_bounds__(1024, 4) void attnE_kernel(
    const f16* __restrict__ qh, const f16* __restrict__ kh,
    const f16* __restrict__ vt, const f16* __restrict__ cpt,
    const float* __restrict__ scalep, float* __restrict__ out) {
  __shared__ __align__(16) f16 liL[16 * LPAD];          // 106,752 B
  __shared__ __align__(16) f16 pstage[NW * 16 * 40];    // 20,480 B
  __shared__ float sl[16][SLPAD];                       // 17,472 B (stride 273: bank-spread)
  __shared__ float totF[NW][16];
  __shared__ float rmxS[NW][16];

  const int tid = (int)threadIdx.x;
  const int lane = tid & 63;
  const int w = wuid();
  const int bt0 = ((int)(gridDim.x - 1 - blockIdx.x)) << 4;
  const int b = bt0 / T_;
  const int t0 = bt0 - b * T_;
  const float sc = scalep[0];
  const int qlo = lane & 15, qhi = lane >> 4;

  const f16* qrp = qh + (size_t)(bt0 + qlo) * 64 + (qhi << 3);
  f16x8 aqh0 = *reinterpret_cast<const f16x8*>(qrp);
  f16x8 aqh1 = *reinterpret_cast<const f16x8*>(qrp + 32);
  const size_t bT64 = (size_t)(b * T_) * 64;

  // ---- phase 1: li rows via MFMA into LDS + rowmax ----
  {
    f32x4 rm = {-1e30f, -1e30f, -1e30f, -1e30f};
    #pragma unroll 2
    for (int c = 0; c < 13; ++c) {
      const int lf = w * 208 + (c << 4);
      const f16* cr = cpt + (size_t)(lf + qlo) * 64 + (qhi << 3);
      f16x8 b0 = *reinterpret_cast<const f16x8*>(cr);
      f16x8 b1 = *reinterpret_cast<const f16x8*>(cr + 32);
      f32x4 a = {0.f, 0.f, 0.f, 0.f};
      a = __builtin_amdgcn_mfma_f32_16x16x32_f16(aqh0, b0, a, 0, 0, 0);
      a = __builtin_amdgcn_mfma_f32_16x16x32_f16(aqh1, b1, a, 0, 0, 0);
      f16 h0_ = (f16)a[0]; liL[((qhi << 2) + 0) * LPAD + lf + qlo] = h0_; rm[0] = fmaxf(rm[0], (float)h0_);
      f16 h1_ = (f16)a[1]; liL[((qhi << 2) + 1) * LPAD + lf + qlo] = h1_; rm[1] = fmaxf(rm[1], (float)h1_);
      f16 h2_ = (f16)a[2]; liL[((qhi << 2) + 2) * LPAD + lf + qlo] = h2_; rm[2] = fmaxf(rm[2], (float)h2_);
      f16 h3_ = (f16)a[3]; liL[((qhi << 2) + 3) * LPAD + lf + qlo] = h3_; rm[3] = fmaxf(rm[3], (float)h3_);
    }
    #pragma unroll
    for (int k = 1; k < 16; k <<= 1) {
      rm[0] = fmaxf(rm[0], __shfl_xor(rm[0], k, 64));
      rm[1] = fmaxf(rm[1], __shfl_xor(rm[1], k, 64));
      rm[2] = fmaxf(rm[2], __shfl_xor(rm[2], k, 64));
      rm[3] = fmaxf(rm[3], __shfl_xor(rm[3], k, 64));
    }
    if (qlo == 0) {
      rmxS[w][(qhi << 2) + 0] = rm[0];
      rmxS[w][(qhi << 2) + 1] = rm[1];
      rmxS[w][(qhi << 2) + 2] = rm[2];
      rmxS[w][(qhi << 2) + 3] = rm[3];
    }
  }

  // ---- phase 1.5: full QK gate slice sums (17 slices per wave) ----
  for (int i = 0; i < 17; ++i) {
    const int sli = w * 17 + i;
    const int sg = (sli << 4) + qlo;
    const f16* krh_ = kh + bT64 + (size_t)sg * 64 + (qhi << 3);
    f16x8 bh0 = *reinterpret_cast<const f16x8*>(krh_);
    f16x8 bh1 = *reinterpret_cast<const f16x8*>(krh_ + 32);
    f32x4 a = {0.f, 0.f, 0.f, 0.f};
    a = __builtin_amdgcn_mfma_f32_16x16x32_f16(aqh0, bh0, a, 0, 0, 0);
    a = __builtin_amdgcn_mfma_f32_16x16x32_f16(aqh1, bh1, a, 0, 0, 0);
    float g0 = 1.f / (1.f + __expf(-a[0])); float s0 = p16scan(g0);
    float g1 = 1.f / (1.f + __expf(-a[1])); float s1 = p16scan(g1);
    float g2 = 1.f / (1.f + __expf(-a[2])); float s2 = p16scan(g2);
    float g3 = 1.f / (1.f + __expf(-a[3])); float s3 = p16scan(g3);
    if (qlo == 15) {
      sl[(qhi << 2) + 0][sli] = s0;
      sl[(qhi << 2) + 1][sli] = s1;
      sl[(qhi << 2) + 2][sli] = s2;
      sl[(qhi << 2) + 3][sli] = s3;
    }
  }
  __syncthreads();

  // ---- phase 1.75: per-row fp64 suffix scan in LDS (wave w owns row w) ----
  {
    const int row = w;
    float* r = &sl[row][0];
    const int base = NSLICE - 1 - 5 * lane;
    double v0 = 0.0, v1 = 0.0, v2 = 0.0, v3 = 0.0, v4 = 0.0;
    double acc = 0.0;
    if (base - 0 >= 0) { acc += (double)r[base - 0]; } v0 = acc;
    if (base - 1 >= 0) { acc += (double)r[base - 1]; } v1 = acc;
    if (base - 2 >= 0) { acc += (double)r[base - 2]; } v2 = acc;
    if (base - 3 >= 0) { acc += (double)r[base - 3]; } v3 = acc;
    if (base - 4 >= 0) { acc += (double)r[base - 4]; } v4 = acc;
    double x = acc;
    #pragma unroll
    for (int off = 1; off < 64; off <<= 1) {
      double y = __shfl_up(x, off, 64);
      if (lane >= off) x += y;
    }
    const double offn = x - acc;
    if (base - 0 >= 0) r[base - 0] = (float)(v0 + offn);
    if (base - 1 >= 0) r[base - 1] = (float)(v1 + offn);
    if (base - 2 >= 0) r[base - 2] = (float)(v2 + offn);
    if (base - 3 >= 0) r[base - 3] = (float)(v3 + offn);
    if (base - 4 >= 0) r[base - 4] = (float)(v4 + offn);
  }

  // mrw (reads rmxS, written before the first barrier)
  f32x4 mrw;
  #pragma unroll
  for (int reg = 0; reg < 4; ++reg) {
    float mm = rmxS[0][(qhi << 2) + reg];
    #pragma unroll
    for (int w2 = 1; w2 < NW; ++w2) mm = fmaxf(mm, rmxS[w2][(qhi << 2) + reg]);
    mrw[reg] = mm + fabsf(sc) + 2e-3f;
  }
  __syncthreads();   // sl suffix-scanned, visible to all

  f16* pst = pstage + w * 640;

  f32x4 o0 = {0.f,0.f,0.f,0.f}, o1 = {0.f,0.f,0.f,0.f};
  f32x4 o2 = {0.f,0.f,0.f,0.f}, o3 = {0.f,0.f,0.f,0.f};
  f32x4 lsum = {0.f,0.f,0.f,0.f};

  const int jtmax = (t0 + 15) >> 9;
  for (int jt = jtmax; jt >= 0; --jt) {
    const int swb = (jt << 9) + (w << 5);
    f32x4 sf0, sf1;
    QKD(sf0, 0) QKD(sf1, 1)
    const int sbr = swb >> 4;
    const int sb0 = sbr < (NSLICE - 1) ? sbr : (NSLICE - 1);
    const int sb1 = (sbr + 1) < (NSLICE - 1) ? (sbr + 1) : (NSLICE - 1);
    float sA0 = sl[(qhi << 2) + 0][sb0];
    float sA1 = sl[(qhi << 2) + 1][sb0];
    float sA2 = sl[(qhi << 2) + 2][sb0];
    float sA3 = sl[(qhi << 2) + 3][sb0];
    float sB0 = sl[(qhi << 2) + 0][sb1];
    float sB1 = sl[(qhi << 2) + 1][sb1];
    float sB2 = sl[(qhi << 2) + 2][sb1];
    float sB3 = sl[(qhi << 2) + 3][sb1];
    // phase A: all scans + all 16 li reads issued together
    float lf0, lc0, wf0, lf1, lc1, wf1, lf2, lc2, wf2, lf3, lc3, wf3;
    float lf4, lc4, wf4, lf5, lc5, wf5, lf6, lc6, wf6, lf7, lc7, wf7;
    PXA(sf0, 0, sA0, lf0, lc0, wf0) PXA(sf0, 1, sA1, lf1, lc1, wf1)
    PXA(sf0, 2, sA2, lf2, lc2, wf2) PXA(sf0, 3, sA3, lf3, lc3, wf3)
    PXA(sf1, 0, sB0, lf4, lc4, wf4) PXA(sf1, 1, sB1, lf5, lc5, wf5)
    PXA(sf1, 2, sB2, lf6, lc6, wf6) PXA(sf1, 3, sB3, lf7, lc7, wf7)
    // phase B: consume
    PXB(sf0, 0, 0, lf0, lc0, wf0) PXB(sf0, 0, 1, lf1, lc1, wf1)
    PXB(sf0, 0, 2, lf2, lc2, wf2) PXB(sf0, 0, 3, lf3, lc3, wf3)
    PXB(sf1, 1, 0, lf4, lc4, wf4) PXB(sf1, 1, 1, lf5, lc5, wf5)
    PXB(sf1, 1, 2, lf6, lc6, wf6) PXB(sf1, 1, 3, lf7, lc7, wf7)
    {
      const f16* pr = pst + qlo * 40;
      f16x8 pa0 = *reinterpret_cast<const f16x8*>(pr + (qhi << 3));
      int sv0 = swb + (qhi << 3);
      sv0 = sv0 < T_ - 8 ? sv0 : T_ - 8;
      PVF(o0, 0) PVF(o1, 1) PVF(o2, 2) PVF(o3, 3)
    }
  }

  #pragma unroll
  for (int k = 1; k < 16; k <<= 1) {
    lsum[0] += __shfl_xor(lsum[0], k, 64);
    lsum[1] += __shfl_xor(lsum[1], k, 64);
    lsum[2] += __shfl_xor(lsum[2], k, 64);
    lsum[3] += __shfl_xor(lsum[3], k, 64);
  }
  __syncthreads();
  if (qlo == 0) {
    totF[w][(qhi << 2) + 0] = lsum[0];
    totF[w][(qhi << 2) + 1] = lsum[1];
    totF[w][(qhi << 2) + 2] = lsum[2];
    totF[w][(qhi << 2) + 3] = lsum[3];
  }
  float* ob = reinterpret_cast<float*>(liL);
  OST(o0, 0) OST(o1, 1) OST(o2, 2) OST(o3, 3)
  __syncthreads();
  {
    const int r = tid >> 6, d = tid & 63;
    float L = 0.f, o = 0.f;
    #pragma unroll
    for (int w2 = 0; w2 < NW; ++w2) {
      L += totF[w2][r];
      o += ob[w2 * 1024 + tid];
    }
    out[(size_t)(bt0 + r) * 64 + d] = o / L;
  }
}

// =================== OLD PATH (fallback, proven) ===================
__global__ __launch_bounds__(256) void wtrans_kernel(
    const float* __restrict__ Wq,  const float* __restrict__ Wk,
    const float* __restrict__ Wv,  const float* __restrict__ Wqs,
    const float* __restrict__ Wks, const float* __restrict__ Wvs,
    float* __restrict__ ws) {
  const int m = blockIdx.y;
  const float* src = (m==0)?Wq:(m==1)?Wqs:(m==2)?Wk:(m==3)?Wks:(m==4)?Wv:Wvs;
  float* dst = ws + (size_t)m * (DIN_*64);
  const int bx = blockIdx.x;
  #pragma unroll
  for (int p = 0; p < 16; ++p) {
    int e = (int)threadIdx.x + (p << 8);
    int c = e & 3, o = (e >> 2) & 63;
    int i = (bx << 6) + (p << 2) + c;
    dst[(((bx << 4) + p) * 64 + o) * 4 + c] = src[o * DIN_ + i];
  }
}

__global__ __launch_bounds__(256) void proj_kernel(
    const float* __restrict__ x, float* __restrict__ ws) {
  __shared__ float tile[32][65];
  const int t0 = blockIdx.x << 5;
  const int b  = blockIdx.y;
  const int pj = blockIdx.z;
  const int spec = (t0 < ST_ || t0 >= ST_ + SEQ_) ? 1 : 0;
  const float4* W4 = reinterpret_cast<const float4*>(ws + WT4_OFF + (size_t)(pj*2 + spec) * (DIN_*64));
  const int lane = (int)threadIdx.x & 63;
  const int w = wuid();
  const float* xb = x + ((size_t)(b * T_ + t0 + (w << 3))) * DIN_;
  float acc[8] = {0.f,0.f,0.f,0.f,0.f,0.f,0.f,0.f};
  #pragma unroll 4
  for (int i4 = 0; i4 < 256; ++i4) {
    float4 wv = W4[(i4 << 6) + lane];
    #pragma unroll
    for (int r = 0; r < 8; ++r) {
      float4 xv = reinterpret_cast<const float4*>(xb + r * DIN_)[i4];
      acc[r] = fmaf(wv.x, xv.x, fmaf(wv.y, xv.y, fmaf(wv.z, xv.z, fmaf(wv.w, xv.w, acc[r]))));
    }
  }
  float outv[8];
  #pragma unroll
  for (int r = 0; r < 8; ++r) {
    float sq = acc[r] * acc[r];
    #pragma unroll
    for (int off = 32; off; off >>= 1) sq += __shfl_xor(sq, off, 64);
    float n = fmaxf(sqrtf(sq), 1e-12f);
    outv[r] = acc[r] / n;
  }
  const int trow = t0 + (w << 3);
  if (pj != 1) {
    float* dst = ws + (pj == 0 ? Q_OFF : V_OFF) + ((size_t)(b * T_ + trow)) * 64;
    #pragma unroll
    for (int r = 0; r < 8; ++r) dst[r * 64 + lane] = outv[r];
  } else {
    #pragma unroll
    for (int r = 0; r < 8; ++r) tile[(w << 3) + r][lane] = outv[r];
    __syncthreads();
    float* kt = ws + KT_OFF + (size_t)b * 16 * T_ * 4;
    #pragma unroll
    for (int p = 0; p < 8; ++p) {
      int e = (int)threadIdx.x + (p << 8);
      int c = e & 3, tt = (e >> 2) & 31, d4 = e >> 7;
      kt[((size_t)d4 * T_ + t0 + tt) * 4 + c] = tile[tt][(d4 << 2) + c];
    }
  }
}

__global__ __launch_bounds__(1024) void attn_kernel(
    const float* __restrict__ ws_c, const float* __restrict__ cope,
    const float* __restrict__ scalep, float* __restrict__ out) {
  __shared__ float li_s[8 * T_];
  __shared__ float pbuf[NW][8][32];
  __shared__ float totF[NW][8];
  __shared__ double suffD[NW][8];
  __shared__ double carryD[2][8];
  __shared__ float mlL[NW][8];
  __shared__ float wmax[NW][8];
  const int tid = (int)threadIdx.x;
  const int lane = tid & 63;
  const int w = wuid();
  const int t0 = ((int)(gridDim.x - 1 - blockIdx.x)) << 3;
  const int b  = blockIdx.y;
  const float* qrow = ws_c + Q_OFF + ((size_t)(b * T_ + t0)) * 64;
  const float* ktb  = ws_c + KT_OFF + (size_t)b * 16 * T_ * 4;
  const float* vb   = ws_c + V_OFF + ((size_t)b * T_) * 64;
  const float sc = scalep[0];
  if (tid < 8) carryD[0][tid] = 0.0;
  float lm[8];
  #pragma unroll
  for (int r = 0; r < 8; ++r) lm[r] = -INFINITY;
  for (int jt = 0; jt < 5; ++jt) {
    const int l = (jt << 10) + tid;
    if (l < T_) {
      float a[8] = {0,0,0,0,0,0,0,0};
      #pragma unroll 4
      for (int d4 = 0; d4 < 16; ++d4) {
        float c0 = cope[(d4 * 4 + 0) * T_ + l];
        float c1 = cope[(d4 * 4 + 1) * T_ + l];
        float c2 = cope[(d4 * 4 + 2) * T_ + l];
        float c3 = cope[(d4 * 4 + 3) * T_ + l];
        #pragma unroll
        for (int r = 0; r < 8; ++r) {
          float4 qq = *reinterpret_cast<const float4*>(qrow + r * 64 + (d4 << 2));
          a[r] = fmaf(c0, qq.x, fmaf(c1, qq.y, fmaf(c2, qq.z, fmaf(c3, qq.w, a[r]))));
        }
      }
      #pragma unroll
      for (int r = 0; r < 8; ++r) { li_s[r * T_ + l] = a[r]; lm[r] = fmaxf(lm[r], a[r]); }
    }
  }
  #pragma unroll
  for (int r = 0; r < 8; ++r) {
    #pragma unroll
    for (int off = 32; off; off >>= 1) lm[r] = fmaxf(lm[r], __shfl_xor(lm[r], off, 64));
  }
  if (lane == 0) {
    #pragma unroll
    for (int r = 0; r < 8; ++r) wmax[w][r] = lm[r];
  }
  __syncthreads();
  float mrow[8];
  #pragma unroll
  for (int r = 0; r < 8; ++r) {
    float mm = wmax[0][r];
    #pragma unroll
    for (int w2 = 1; w2 < NW; ++w2) mm = fmaxf(mm, wmax[w2][r]);
    mrow[r] = mm + fabsf(sc) + 1e-3f;
  }
  float acc[8]  = {0,0,0,0,0,0,0,0};
  float lsum[8] = {0,0,0,0,0,0,0,0};
  int par = 0;
  for (int jt = 4; jt >= 0; --jt) {
    const int s = (jt << 10) + tid;
    const bool sval = (s < T_);
    float lg[8] = {0,0,0,0,0,0,0,0};
    if (sval) {
      #pragma unroll 4
      for (int d4 = 0; d4 < 16; ++d4) {
        float4 kk = *reinterpret_cast<const float4*>(ktb + ((size_t)d4 * T_ + s) * 4);
        #pragma unroll
        for (int r = 0; r < 8; ++r) {
          float4 qq = *reinterpret_cast<const float4*>(qrow + r * 64 + (d4 << 2));
          lg[r] = fmaf(kk.x, qq.x, fmaf(kk.y, qq.y, fmaf(kk.z, qq.z, fmaf(kk.w, qq.w, lg[r]))));
        }
      }
    }
    float locsuf[8], gtot[8];
    #pragma unroll
    for (int r = 0; r < 8; ++r) {
      float g = sval ? 1.f / (1.f + __expf(-lg[r])) : 0.f;
      float xx = wave_iscan(g);
      float tt = __shfl(xx, 63, 64);
      locsuf[r] = tt - xx + g;
      gtot[r] = tt;
    }
    if (lane == 0) {
      #pragma unroll
      for (int r = 0; r < 8; ++r) totF[w][r] = gtot[r];
    }
    __syncthreads();
    if (tid < 128) {
      const int w2 = tid >> 3, r = tid & 7;
      float ssum = 0.f;
      for (int w3 = w2 + 1; w3 < NW; ++w3) ssum += totF[w3][r];
      suffD[w2][r] = carryD[par][r] + (double)ssum;
      if (w2 == 0) carryD[par ^ 1][r] = carryD[par][r] + (double)(ssum + totF[0][r]);
    }
    __syncthreads();
    par ^= 1;
    if ((jt << 10) > t0 + 7) continue;
    float p[8];
    #pragma unroll
    for (int r = 0; r < 8; ++r) {
      double posd = suffD[w][r] + (double)locsuf[r];
      if (posd > 4351.0) posd = 4351.0;
      int idx = (int)posd;
      float wf = (float)(posd - (double)idx);
      int idx2 = idx < 4351 ? idx + 1 : 4351;
      float lf = li_s[r * T_ + idx];
      float lc = li_s[r * T_ + idx2];
      float bias = fmaf(wf, lc - lf, lf);
      const int t = t0 + r;
      const bool valid = sval && (s <= t) && !((t >= ST_ + SEQ_) && (s < ST_));
      float score = valid ? fmaf(lg[r], sc, bias) : -INFINITY;
      p[r] = __expf(score - mrow[r]);
      lsum[r] += p[r];
    }
    const int sbase = (jt << 10) + (w << 6);
    if (sbase < T_) {
      #pragma unroll
      for (int pass = 0; pass < 2; ++pass) {
        if ((lane >> 5) == pass) {
          #pragma unroll
          for (int r = 0; r < 8; ++r) pbuf[w][r][lane & 31] = p[r];
        }
        const int s0 = sbase + (pass << 5);
        #pragma unroll 4
        for (int s4 = 0; s4 < 8; ++s4) {
          const int sb = s0 + (s4 << 2);
          float v0 = vb[(size_t)(sb + 0) * 64 + lane];
          float v1 = vb[(size_t)(sb + 1) * 64 + lane];
          float v2 = vb[(size_t)(sb + 2) * 64 + lane];
          float v3 = vb[(size_t)(sb + 3) * 64 + lane];
          #pragma unroll
          for (int r = 0; r < 8; ++r) {
            float4 pr = *reinterpret_cast<const float4*>(&pbuf[w][r][s4 << 2]);
            acc[r] = fmaf(pr.x, v0, fmaf(pr.y, v1, fmaf(pr.z, v2, fmaf(pr.w, v3, acc[r]))));
          }
        }
      }
    }
  }
  #pragma unroll
  for (int r = 0; r < 8; ++r) {
    #pragma unroll
    for (int off = 32; off; off >>= 1) lsum[r] += __shfl_xor(lsum[r], off, 64);
  }
  if (lane == 0) {
    #pragma unroll
    for (int r = 0; r < 8; ++r) mlL[w][r] = lsum[r];
  }
  float* pb = &pbuf[w][0][0];
  #pragma unroll
  for (int pass = 0; pass < 2; ++pass) {
    __syncthreads();
    #pragma unroll
    for (int rr = 0; rr < 4; ++rr) pb[rr * 64 + lane] = acc[pass * 4 + rr];
    __syncthreads();
    if (tid < 256) {
      const int rr = tid >> 6, d = tid & 63;
      const int r = pass * 4 + rr;
      float o = 0.f, L = 0.f;
      #pragma unroll
      for (int w2 = 0; w2 < NW; ++w2) {
        o += (&pbuf[w2][0][0])[rr * 64 + d];
        L += mlL[w2][r];
      }
      out[((size_t)(b * T_ + t0 + r)) * 64 + d] = o / L;
    }
  }
}

extern "C" void kernel_launch(void* const* d_in, const int* in_sizes, int n_in,
                              void* d_out, int out_size, void* d_ws, size_t ws_size,
                              hipStream_t stream) {
  const float* x    = (const float*)d_in[0];
  const float* Wq   = (const float*)d_in[1];
  const float* Wk   = (const float*)d_in[2];
  const float* Wv   = (const float*)d_in[3];
  const float* Wqs  = (const float*)d_in[4];
  const float* Wks  = (const float*)d_in[5];
  const float* Wvs  = (const float*)d_in[6];
  const float* cope = (const float*)d_in[7];
  const float* scl  = (const float*)d_in[8];
  float* outp = (float*)d_out;
  (void)in_sizes; (void)n_in; (void)out_size;

  if (ws_size >= NEED_NEW) {
    unsigned char* wb = (unsigned char*)d_ws;
    f16* whp = (f16*)(wb + OB_WH);
    f16* wlp = (f16*)(wb + OB_WL);
    f16* qh = (f16*)(wb + OB_QH);
    f16* ql = (f16*)(wb + OB_QL);
    f16* kh = (f16*)(wb + OB_KH);
    f16* kl = (f16*)(wb + OB_KL);
    f16* vt = (f16*)(wb + OB_VT);
    f16* cpt = (f16*)(wb + OB_CPT);
    f16* xhp = (f16*)(wb + OB_XH);
    f16* xlp = (f16*)(wb + OB_XL);
    hipLaunchKernelGGL(wsplit_kernel, dim3(16, 6), dim3(256), 0, stream,
                       Wq, Wk, Wv, Wqs, Wks, Wvs, whp, wlp);
    hipLaunchKernelGGL(xsplit_kernel, dim3(2176), dim3(256), 0, stream, x, xhp, xlp);
    hipLaunchKernelGGL(copet_kernel, dim3(52), dim3(256), 0, stream, cope, cpt);
    hipLaunchKernelGGL(projM_kernel, dim3(544), dim3(512), 0, stream,
                       xhp, xlp, whp, wlp, qh, ql, kh, kl, vt);
    hipLaunchKernelGGL(attnE_kernel, dim3(544), dim3(1024), 0, stream,
                       qh, kh, vt, cpt, scl, outp);
  } else {
    float* ws = (float*)d_ws;
    hipLaunchKernelGGL(wtrans_kernel, dim3(16, 6), dim3(256), 0, stream,
                       Wq, Wk, Wv, Wqs, Wks, Wvs, ws);
    hipLaunchKernelGGL(proj_kernel, dim3(136, 2, 3), dim3(256), 0, stream, x, ws);
    hipLaunchKernelGGL(attn_kernel, dim3(544, 2), dim3(1024), 0, stream, ws, cope, scl, outp);
  }
}

// Round 17
// 236.843 us; speedup vs baseline: 1.0591x; 1.0591x over previous
//
#include <hip/hip_runtime.h>
#include <math.h>

#define B_ 2
#define SEQ_ 4096
#define ST_ 128
#define T_ 4352
#define DIN_ 1024
#define NW 16
#define LMAX 3328
#define LPAD 3336
#define NSLICE 272
#define SLPAD 273

typedef _Float16 f16;
typedef __attribute__((ext_vector_type(8))) _Float16 f16x8;
typedef __attribute__((ext_vector_type(4))) float f32x4;

// ---- new-path ws byte offsets ----
#define OB_WH  0                 // 6*64*1024*2 = 786432
#define OB_WL  786432
#define OB_QH  1572864           // 8704*64*2 = 1114112
#define OB_KH  2686976
#define OB_VT  3801088
#define OB_CPT 4915200           // 3328*64*2 = 425984
#define NEED_NEW 5341184ull

// ---- old-path ws float offsets ----
#define WT4_OFF 0
#define Q_OFF   393216
#define KT_OFF  950272
#define V_OFF   1507328

__device__ __forceinline__ int wuid() {
  return __builtin_amdgcn_readfirstlane((int)(threadIdx.x >> 6));
}

template<int CTRL, int RM>
__device__ __forceinline__ float dppadd(float x) {
  int y = __builtin_amdgcn_update_dpp(0, __float_as_int(x), CTRL, RM, 0xf, true);
  return x + __int_as_float(y);
}
__device__ __forceinline__ float wave_iscan(float x) {
  x = dppadd<0x111, 0xf>(x);
  x = dppadd<0x112, 0xf>(x);
  x = dppadd<0x114, 0xf>(x);
  x = dppadd<0x118, 0xf>(x);
  x = dppadd<0x142, 0xa>(x);
  x = dppadd<0x143, 0xc>(x);
  return x;
}
__device__ __forceinline__ float p16scan(float x) {
  x = dppadd<0x111, 0xf>(x);
  x = dppadd<0x112, 0xf>(x);
  x = dppadd<0x114, 0xf>(x);
  x = dppadd<0x118, 0xf>(x);
  return x;
}
__device__ __forceinline__ float swz15(float x) {
  return __int_as_float(__builtin_amdgcn_ds_swizzle(__float_as_int(x), 0x1F0));
}

// ---------------- prep: W split (96 blocks) + cope transpose (52 blocks) ----------------
__global__ __launch_bounds__(256) void prep_kernel(
    const float* __restrict__ Wq,  const float* __restrict__ Wk,
    const float* __restrict__ Wv,  const float* __restrict__ Wqs,
    const float* __restrict__ Wks, const float* __restrict__ Wvs,
    const float* __restrict__ cope,
    f16* __restrict__ wh, f16* __restrict__ wl, f16* __restrict__ copeT) {
  __shared__ float t2[64][65];
  const int id = (int)blockIdx.x;
  const int tid = (int)threadIdx.x;
  if (id < 96) {
    const int m = id >> 4;
    const float* src = (m==0)?Wq:(m==1)?Wqs:(m==2)?Wk:(m==3)?Wks:(m==4)?Wv:Wvs;
    const int g0 = (id & 15) * 4096 + tid * 16;
    const float4* s4 = reinterpret_cast<const float4*>(src + g0);
    float4 v0 = s4[0], v1 = s4[1], v2 = s4[2], v3 = s4[3];
    f16x8 h0, h1, l0, l1;
    h0[0]=(f16)v0.x; h0[1]=(f16)v0.y; h0[2]=(f16)v0.z; h0[3]=(f16)v0.w;
    h0[4]=(f16)v1.x; h0[5]=(f16)v1.y; h0[6]=(f16)v1.z; h0[7]=(f16)v1.w;
    h1[0]=(f16)v2.x; h1[1]=(f16)v2.y; h1[2]=(f16)v2.z; h1[3]=(f16)v2.w;
    h1[4]=(f16)v3.x; h1[5]=(f16)v3.y; h1[6]=(f16)v3.z; h1[7]=(f16)v3.w;
    l0[0]=(f16)(v0.x-(float)h0[0]); l0[1]=(f16)(v0.y-(float)h0[1]);
    l0[2]=(f16)(v0.z-(float)h0[2]); l0[3]=(f16)(v0.w-(float)h0[3]);
    l0[4]=(f16)(v1.x-(float)h0[4]); l0[5]=(f16)(v1.y-(float)h0[5]);
    l0[6]=(f16)(v1.z-(float)h0[6]); l0[7]=(f16)(v1.w-(float)h0[7]);
    l1[0]=(f16)(v2.x-(float)h1[0]); l1[1]=(f16)(v2.y-(float)h1[1]);
    l1[2]=(f16)(v2.z-(float)h1[2]); l1[3]=(f16)(v2.w-(float)h1[3]);
    l1[4]=(f16)(v3.x-(float)h1[4]); l1[5]=(f16)(v3.y-(float)h1[5]);
    l1[6]=(f16)(v3.z-(float)h1[6]); l1[7]=(f16)(v3.w-(float)h1[7]);
    const size_t o = (size_t)m * 65536 + g0;
    *reinterpret_cast<f16x8*>(wh + o) = h0;
    *reinterpret_cast<f16x8*>(wh + o + 8) = h1;
    *reinterpret_cast<f16x8*>(wl + o) = l0;
    *reinterpret_cast<f16x8*>(wl + o + 8) = l1;
  } else {
    const int l0i = (id - 96) << 6;
    #pragma unroll
    for (int p = 0; p < 16; ++p) {
      int d = (p << 2) + (tid >> 6), c = tid & 63;
      t2[d][c] = cope[(size_t)d * T_ + l0i + c];
    }
    __syncthreads();
    #pragma unroll
    for (int p = 0; p < 16; ++p) {
      int l = (p << 2) + (tid >> 6), d = tid & 63;
      copeT[(size_t)(l0i + l) * 64 + d] = (f16)t2[d][l];
    }
  }
}

// ======== projM macros (3-pass; 8-wave K-split; inline x split) ========
#define PM_MFMA(ACC, WHP, WLP) { \
  f16x8 bh_ = *reinterpret_cast<const f16x8*>((WHP) + (st << 5)); \
  f16x8 bl_ = *reinterpret_cast<const f16x8*>((WLP) + (st << 5)); \
  ACC = __builtin_amdgcn_mfma_f32_16x16x32_f16(xh_, bh_, ACC, 0, 0, 0); \
  ACC = __builtin_amdgcn_mfma_f32_16x16x32_f16(xl_, bh_, ACC, 0, 0, 0); \
  ACC = __builtin_amdgcn_mfma_f32_16x16x32_f16(xh_, bl_, ACC, 0, 0, 0); }

#define PM_RED(ACC, P) { \
  float s0_ = ACC[0]*ACC[0], s1_ = ACC[1]*ACC[1], s2_ = ACC[2]*ACC[2], s3_ = ACC[3]*ACC[3]; \
  s0_ += __shfl_xor(s0_, 1, 64); s1_ += __shfl_xor(s1_, 1, 64); \
  s2_ += __shfl_xor(s2_, 1, 64); s3_ += __shfl_xor(s3_, 1, 64); \
  s0_ += __shfl_xor(s0_, 2, 64); s1_ += __shfl_xor(s1_, 2, 64); \
  s2_ += __shfl_xor(s2_, 2, 64); s3_ += __shfl_xor(s3_, 2, 64); \
  s0_ += __shfl_xor(s0_, 4, 64); s1_ += __shfl_xor(s1_, 4, 64); \
  s2_ += __shfl_xor(s2_, 4, 64); s3_ += __shfl_xor(s3_, 4, 64); \
  s0_ += __shfl_xor(s0_, 8, 64); s1_ += __shfl_xor(s1_, 8, 64); \
  s2_ += __shfl_xor(s2_, 8, 64); s3_ += __shfl_xor(s3_, 8, 64); \
  if (qlo == 0) { \
    ssq[wn][P][(qhi << 2) + 0] = s0_; ssq[wn][P][(qhi << 2) + 1] = s1_; \
    ssq[wn][P][(qhi << 2) + 2] = s2_; ssq[wn][P][(qhi << 2) + 3] = s3_; } }

#define PM_QK1(ACC, P, HH, RG) { \
  float tt_ = ssq[0][P][(qhi << 2) + RG] + ssq[1][P][(qhi << 2) + RG] \
            + ssq[2][P][(qhi << 2) + RG] + ssq[3][P][(qhi << 2) + RG]; \
  float rn_ = 1.f / fmaxf(sqrtf(tt_), 1e-12f); \
  float v_ = ACC[RG] * rn_; \
  HH[(size_t)(bt0 + (qhi << 2) + RG) * 64 + (wn << 4) + qlo] = (f16)v_; }

#define PM_V1(ACC, P, RG) { \
  float tt_ = ssq[0][P][(qhi << 2) + RG] + ssq[1][P][(qhi << 2) + RG] \
            + ssq[2][P][(qhi << 2) + RG] + ssq[3][P][(qhi << 2) + RG]; \
  float rn_ = 1.f / fmaxf(sqrtf(tt_), 1e-12f); \
  vt[(size_t)(b * 64 + (wn << 4) + qlo) * T_ + t0 + (qhi << 2) + RG] = (f16)(ACC[RG] * rn_); }

// ---------------- MFMA projections + l2norm (8 waves, K-split, inline x split) ----------------
__global__ __launch_bounds__(512, 4) void projM_kernel(
    const float* __restrict__ x,
    const f16* __restrict__ wh, const f16* __restrict__ wl,
    f16* __restrict__ qh, f16* __restrict__ kh, f16* __restrict__ vt) {
  __shared__ float ssq[4][3][16];
  __shared__ float part[4][64][12];
  const int lane = (int)threadIdx.x & 63;
  const int w = wuid();
  const int wn = w & 3;
  const int kh2 = w >> 2;
  const int qlo = lane & 15, qhi = lane >> 4;
  const int bt0 = (int)blockIdx.x << 4;
  const int b = bt0 / T_;
  const int t0 = bt0 - b * T_;
  const int spec = (t0 < ST_ || t0 >= ST_ + SEQ_) ? 1 : 0;

  const int kof = kh2 << 9;
  const float* xr = x + (size_t)(bt0 + qlo) * DIN_ + kof + (qhi << 3);
  const size_t wrow = (size_t)((wn << 4) + qlo) * 1024 + kof + (qhi << 3);
  const f16* wq  = wh + (size_t)(0 + spec) * 65536 + wrow;
  const f16* wqL = wl + (size_t)(0 + spec) * 65536 + wrow;
  const f16* wk  = wh + (size_t)(2 + spec) * 65536 + wrow;
  const f16* wkL = wl + (size_t)(2 + spec) * 65536 + wrow;
  const f16* wv  = wh + (size_t)(4 + spec) * 65536 + wrow;
  const f16* wvL = wl + (size_t)(4 + spec) * 65536 + wrow;

  f32x4 aq = {0.f,0.f,0.f,0.f}, ak = {0.f,0.f,0.f,0.f}, av = {0.f,0.f,0.f,0.f};

  #pragma unroll 2
  for (int st = 0; st < 16; ++st) {
    float4 xa_ = *reinterpret_cast<const float4*>(xr + (st << 5));
    float4 xb_ = *reinterpret_cast<const float4*>(xr + (st << 5) + 4);
    f16x8 xh_, xl_;
    xh_[0]=(f16)xa_.x; xh_[1]=(f16)xa_.y; xh_[2]=(f16)xa_.z; xh_[3]=(f16)xa_.w;
    xh_[4]=(f16)xb_.x; xh_[5]=(f16)xb_.y; xh_[6]=(f16)xb_.z; xh_[7]=(f16)xb_.w;
    xl_[0]=(f16)(xa_.x-(float)xh_[0]); xl_[1]=(f16)(xa_.y-(float)xh_[1]);
    xl_[2]=(f16)(xa_.z-(float)xh_[2]); xl_[3]=(f16)(xa_.w-(float)xh_[3]);
    xl_[4]=(f16)(xb_.x-(float)xh_[4]); xl_[5]=(f16)(xb_.y-(float)xh_[5]);
    xl_[6]=(f16)(xb_.z-(float)xh_[6]); xl_[7]=(f16)(xb_.w-(float)xh_[7]);
    PM_MFMA(aq, wq, wqL)
    PM_MFMA(ak, wk, wkL)
    PM_MFMA(av, wv, wvL)
  }

  if (w >= 4) {
    float* p = &part[w - 4][lane][0];
    p[0] = aq[0]; p[1] = aq[1]; p[2]  = aq[2]; p[3]  = aq[3];
    p[4] = ak[0]; p[5] = ak[1]; p[6]  = ak[2]; p[7]  = ak[3];
    p[8] = av[0]; p[9] = av[1]; p[10] = av[2]; p[11] = av[3];
  }
  __syncthreads();
  if (w < 4) {
    const float* p = &part[w][lane][0];
    aq[0] += p[0]; aq[1] += p[1]; aq[2] += p[2];  aq[3] += p[3];
    ak[0] += p[4]; ak[1] += p[5]; ak[2] += p[6];  ak[3] += p[7];
    av[0] += p[8]; av[1] += p[9]; av[2] += p[10]; av[3] += p[11];
    PM_RED(aq, 0) PM_RED(ak, 1) PM_RED(av, 2)
  }
  __syncthreads();
  if (w < 4) {
    PM_QK1(aq, 0, qh, 0) PM_QK1(aq, 0, qh, 1)
    PM_QK1(aq, 0, qh, 2) PM_QK1(aq, 0, qh, 3)
    PM_QK1(ak, 1, kh, 0) PM_QK1(ak, 1, kh, 1)
    PM_QK1(ak, 1, kh, 2) PM_QK1(ak, 1, kh, 3)
    PM_V1(av, 2, 0) PM_V1(av, 2, 1) PM_V1(av, 2, 2) PM_V1(av, 2, 3)
  }
}

// ======== attnE macros (single-pass QK; PX split; in-LDS ss) ========
#define QKD(SF, NF) { \
  int sg_ = swb + (NF << 4) + qlo; \
  int scl_ = sg_ < T_ ? sg_ : T_ - 1; \
  const f16* krh_ = kh + bT64 + (size_t)scl_ * 64 + (qhi << 3); \
  f16x8 bh0_ = *reinterpret_cast<const f16x8*>(krh_); \
  f16x8 bh1_ = *reinterpret_cast<const f16x8*>(krh_ + 32); \
  f32x4 a_ = {0.f, 0.f, 0.f, 0.f}; \
  a_ = __builtin_amdgcn_mfma_f32_16x16x32_f16(aqh0, bh0_, a_, 0, 0, 0); \
  a_ = __builtin_amdgcn_mfma_f32_16x16x32_f16(aqh1, bh1_, a_, 0, 0, 0); \
  SF = a_; }

#define PXA(SF, RG, SSV, LF, LC, WF) { \
  float g_ = 1.f / (1.f + __expf(-SF[RG])); \
  float in_ = p16scan(g_); \
  float pos_ = SSV - in_ + g_; \
  pos_ = pos_ < 0.f ? 0.f : (pos_ > 3326.f ? 3326.f : pos_); \
  int idx_ = (int)pos_; \
  WF = pos_ - (float)idx_; \
  const f16* lrow_ = liL + ((qhi << 2) + RG) * LPAD + idx_; \
  LF = (float)lrow_[0]; LC = (float)lrow_[1]; }

#define PXB(SF, NF, RG, LF, LC, WF) { \
  int sg_ = swb + (NF << 4) + qlo; \
  float bias_ = fmaf(WF, LC - LF, LF); \
  int tl_ = t0 + (qhi << 2) + RG; \
  bool valid_ = (sg_ <= tl_) && !((tl_ >= ST_ + SEQ_) && (sg_ < ST_)); \
  float p_ = valid_ ? __expf(fmaf(SF[RG], sc, bias_) - mrw[RG]) : 0.f; \
  lsum[RG] += p_; \
  pst[((qhi << 2) + RG) * 40 + (NF << 4) + qlo] = (f16)p_; }

#define PVF(OA, NF) { \
  int d_ = (NF << 4) + qlo; \
  const f16* vr_ = vt + (size_t)(b * 64 + d_) * T_; \
  f16x8 v0_ = *reinterpret_cast<const f16x8*>(vr_ + sv0); \
  OA = __builtin_amdgcn_mfma_f32_16x16x32_f16(pa0, v0_, OA, 0, 0, 0); }

#define OST(OA, NF) { \
  ob[w * 1024 + ((qhi << 2) + 0) * 64 + (NF << 4) + qlo] = OA[0]; \
  ob[w * 1024 + ((qhi << 2) + 1) * 64 + (NF << 4) + qlo] = OA[1]; \
  ob[w * 1024 + ((qhi << 2) + 2) * 64 + (NF << 4) + qlo] = OA[2]; \
  ob[w * 1024 + ((qhi << 2) + 3) * 64 + (NF << 4) + qlo] = OA[3]; }

// ---------------- fused attention: gscan + barrier-free causal sweep ----------------
__global__ __launch_bounds__(1024, 4) void attnE_kernel(
    const f16* __restrict__ qh, const f16* __restrict__ kh,
    const f16* __restrict__ vt, const f16* __restrict__ cpt,
    const float* __restrict__ scalep, float* __restrict__ out) {
  __shared__ __align__(16) f16 liL[16 * LPAD];
  __shared__ __align__(16) f16 pstage[NW * 16 * 40];
  __shared__ float sl[16][SLPAD];
  __shared__ float totF[NW][16];
  __shared__ float rmxS[NW][16];

  const int tid = (int)threadIdx.x;
  const int lane = tid & 63;
  const int w = wuid();
  const int bt0 = ((int)(gridDim.x - 1 - blockIdx.x)) << 4;
  const int b = bt0 / T_;
  const int t0 = bt0 - b * T_;
  const float sc = scalep[0];
  const int qlo = lane & 15, qhi = lane >> 4;

  const f16* qrp = qh + (size_t)(bt0 + qlo) * 64 + (qhi << 3);
  f16x8 aqh0 = *reinterpret_cast<const f16x8*>(qrp);
  f16x8 aqh1 = *reinterpret_cast<const f16x8*>(qrp + 32);
  const size_t bT64 = (size_t)(b * T_) * 64;

  // ---- phase 1: li rows via MFMA into LDS + rowmax ----
  {
    f32x4 rm = {-1e30f, -1e30f, -1e30f, -1e30f};
    #pragma unroll 2
    for (int c = 0; c < 13; ++c) {
      const int lf = w * 208 + (c << 4);
      const f16* cr = cpt + (size_t)(lf + qlo) * 64 + (qhi << 3);
      f16x8 b0 = *reinterpret_cast<const f16x8*>(cr);
      f16x8 b1 = *reinterpret_cast<const f16x8*>(cr + 32);
      f32x4 a = {0.f, 0.f, 0.f, 0.f};
      a = __builtin_amdgcn_mfma_f32_16x16x32_f16(aqh0, b0, a, 0, 0, 0);
      a = __builtin_amdgcn_mfma_f32_16x16x32_f16(aqh1, b1, a, 0, 0, 0);
      f16 h0_ = (f16)a[0]; liL[((qhi << 2) + 0) * LPAD + lf + qlo] = h0_; rm[0] = fmaxf(rm[0], (float)h0_);
      f16 h1_ = (f16)a[1]; liL[((qhi << 2) + 1) * LPAD + lf + qlo] = h1_; rm[1] = fmaxf(rm[1], (float)h1_);
      f16 h2_ = (f16)a[2]; liL[((qhi << 2) + 2) * LPAD + lf + qlo] = h2_; rm[2] = fmaxf(rm[2], (float)h2_);
      f16 h3_ = (f16)a[3]; liL[((qhi << 2) + 3) * LPAD + lf + qlo] = h3_; rm[3] = fmaxf(rm[3], (float)h3_);
    }
    #pragma unroll
    for (int k = 1; k < 16; k <<= 1) {
      rm[0] = fmaxf(rm[0], __shfl_xor(rm[0], k, 64));
      rm[1] = fmaxf(rm[1], __shfl_xor(rm[1], k, 64));
      rm[2] = fmaxf(rm[2], __shfl_xor(rm[2], k, 64));
      rm[3] = fmaxf(rm[3], __shfl_xor(rm[3], k, 64));
    }
    if (qlo == 0) {
      rmxS[w][(qhi << 2) + 0] = rm[0];
      rmxS[w][(qhi << 2) + 1] = rm[1];
      rmxS[w][(qhi << 2) + 2] = rm[2];
      rmxS[w][(qhi << 2) + 3] = rm[3];
    }
  }

  // ---- phase 1.5: full QK gate slice sums (17 slices per wave) ----
  for (int i = 0; i < 17; ++i) {
    const int sli = w * 17 + i;
    const int sg = (sli << 4) + qlo;
    const f16* krh_ = kh + bT64 + (size_t)sg * 64 + (qhi << 3);
    f16x8 bh0 = *reinterpret_cast<const f16x8*>(krh_);
    f16x8 bh1 = *reinterpret_cast<const f16x8*>(krh_ + 32);
    f32x4 a = {0.f, 0.f, 0.f, 0.f};
    a = __builtin_amdgcn_mfma_f32_16x16x32_f16(aqh0, bh0, a, 0, 0, 0);
    a = __builtin_amdgcn_mfma_f32_16x16x32_f16(aqh1, bh1, a, 0, 0, 0);
    float g0 = 1.f / (1.f + __expf(-a[0])); float s0 = p16scan(g0);
    float g1 = 1.f / (1.f + __expf(-a[1])); float s1 = p16scan(g1);
    float g2 = 1.f / (1.f + __expf(-a[2])); float s2 = p16scan(g2);
    float g3 = 1.f / (1.f + __expf(-a[3])); float s3 = p16scan(g3);
    if (qlo == 15) {
      sl[(qhi << 2) + 0][sli] = s0;
      sl[(qhi << 2) + 1][sli] = s1;
      sl[(qhi << 2) + 2][sli] = s2;
      sl[(qhi << 2) + 3][sli] = s3;
    }
  }
  __syncthreads();

  // ---- phase 1.75: per-row fp64 suffix scan in LDS (wave w owns row w) ----
  {
    float* r = &sl[w][0];
    const int base = NSLICE - 1 - 5 * lane;
    double v0 = 0.0, v1 = 0.0, v2 = 0.0, v3 = 0.0, v4 = 0.0;
    double acc = 0.0;
    if (base - 0 >= 0) { acc += (double)r[base - 0]; } v0 = acc;
    if (base - 1 >= 0) { acc += (double)r[base - 1]; } v1 = acc;
    if (base - 2 >= 0) { acc += (double)r[base - 2]; } v2 = acc;
    if (base - 3 >= 0) { acc += (double)r[base - 3]; } v3 = acc;
    if (base - 4 >= 0) { acc += (double)r[base - 4]; } v4 = acc;
    double x = acc;
    #pragma unroll
    for (int off = 1; off < 64; off <<= 1) {
      double y = __shfl_up(x, off, 64);
      if (lane >= off) x += y;
    }
    const double offn = x - acc;
    if (base - 0 >= 0) r[base - 0] = (float)(v0 + offn);
    if (base - 1 >= 0) r[base - 1] = (float)(v1 + offn);
    if (base - 2 >= 0) r[base - 2] = (float)(v2 + offn);
    if (base - 3 >= 0) r[base - 3] = (float)(v3 + offn);
    if (base - 4 >= 0) r[base - 4] = (float)(v4 + offn);
  }

  f32x4 mrw;
  #pragma unroll
  for (int reg = 0; reg < 4; ++reg) {
    float mm = rmxS[0][(qhi << 2) + reg];
    #pragma unroll
    for (int w2 = 1; w2 < NW; ++w2) mm = fmaxf(mm, rmxS[w2][(qhi << 2) + reg]);
    mrw[reg] = mm + fabsf(sc) + 2e-3f;
  }
  __syncthreads();

  f16* pst = pstage + w * 640;

  f32x4 o0 = {0.f,0.f,0.f,0.f}, o1 = {0.f,0.f,0.f,0.f};
  f32x4 o2 = {0.f,0.f,0.f,0.f}, o3 = {0.f,0.f,0.f,0.f};
  f32x4 lsum = {0.f,0.f,0.f,0.f};

  const int jtmax = (t0 + 15) >> 9;
  for (int jt = jtmax; jt >= 0; --jt) {
    const int swb = (jt << 9) + (w << 5);
    f32x4 sf0, sf1;
    QKD(sf0, 0) QKD(sf1, 1)
    const int sbr = swb >> 4;
    const int sb0 = sbr < (NSLICE - 1) ? sbr : (NSLICE - 1);
    const int sb1 = (sbr + 1) < (NSLICE - 1) ? (sbr + 1) : (NSLICE - 1);
    float sA0 = sl[(qhi << 2) + 0][sb0];
    float sA1 = sl[(qhi << 2) + 1][sb0];
    float sA2 = sl[(qhi << 2) + 2][sb0];
    float sA3 = sl[(qhi << 2) + 3][sb0];
    float sB0 = sl[(qhi << 2) + 0][sb1];
    float sB1 = sl[(qhi << 2) + 1][sb1];
    float sB2 = sl[(qhi << 2) + 2][sb1];
    float sB3 = sl[(qhi << 2) + 3][sb1];
    float lf0, lc0, wf0, lf1, lc1, wf1, lf2, lc2, wf2, lf3, lc3, wf3;
    float lf4, lc4, wf4, lf5, lc5, wf5, lf6, lc6, wf6, lf7, lc7, wf7;
    PXA(sf0, 0, sA0, lf0, lc0, wf0) PXA(sf0, 1, sA1, lf1, lc1, wf1)
    PXA(sf0, 2, sA2, lf2, lc2, wf2) PXA(sf0, 3, sA3, lf3, lc3, wf3)
    PXA(sf1, 0, sB0, lf4, lc4, wf4) PXA(sf1, 1, sB1, lf5, lc5, wf5)
    PXA(sf1, 2, sB2, lf6, lc6, wf6) PXA(sf1, 3, sB3, lf7, lc7, wf7)
    PXB(sf0, 0, 0, lf0, lc0, wf0) PXB(sf0, 0, 1, lf1, lc1, wf1)
    PXB(sf0, 0, 2, lf2, lc2, wf2) PXB(sf0, 0, 3, lf3, lc3, wf3)
    PXB(sf1, 1, 0, lf4, lc4, wf4) PXB(sf1, 1, 1, lf5, lc5, wf5)
    PXB(sf1, 1, 2, lf6, lc6, wf6) PXB(sf1, 1, 3, lf7, lc7, wf7)
    {
      const f16* pr = pst + qlo * 40;
      f16x8 pa0 = *reinterpret_cast<const f16x8*>(pr + (qhi << 3));
      int sv0 = swb + (qhi << 3);
      sv0 = sv0 < T_ - 8 ? sv0 : T_ - 8;
      PVF(o0, 0) PVF(o1, 1) PVF(o2, 2) PVF(o3, 3)
    }
  }

  #pragma unroll
  for (int k = 1; k < 16; k <<= 1) {
    lsum[0] += __shfl_xor(lsum[0], k, 64);
    lsum[1] += __shfl_xor(lsum[1], k, 64);
    lsum[2] += __shfl_xor(lsum[2], k, 64);
    lsum[3] += __shfl_xor(lsum[3], k, 64);
  }
  __syncthreads();
  if (qlo == 0) {
    totF[w][(qhi << 2) + 0] = lsum[0];
    totF[w][(qhi << 2) + 1] = lsum[1];
    totF[w][(qhi << 2) + 2] = lsum[2];
    totF[w][(qhi << 2) + 3] = lsum[3];
  }
  float* ob = reinterpret_cast<float*>(liL);
  OST(o0, 0) OST(o1, 1) OST(o2, 2) OST(o3, 3)
  __syncthreads();
  {
    const int r = tid >> 6, d = tid & 63;
    float L = 0.f, o = 0.f;
    #pragma unroll
    for (int w2 = 0; w2 < NW; ++w2) {
      L += totF[w2][r];
      o += ob[w2 * 1024 + tid];
    }
    out[(size_t)(bt0 + r) * 64 + d] = o / L;
  }
}

// =================== OLD PATH (fallback, proven) ===================
__global__ __launch_bounds__(256) void wtrans_kernel(
    const float* __restrict__ Wq,  const float* __restrict__ Wk,
    const float* __restrict__ Wv,  const float* __restrict__ Wqs,
    const float* __restrict__ Wks, const float* __restrict__ Wvs,
    float* __restrict__ ws) {
  const int m = blockIdx.y;
  const float* src = (m==0)?Wq:(m==1)?Wqs:(m==2)?Wk:(m==3)?Wks:(m==4)?Wv:Wvs;
  float* dst = ws + (size_t)m * (DIN_*64);
  const int bx = blockIdx.x;
  #pragma unroll
  for (int p = 0; p < 16; ++p) {
    int e = (int)threadIdx.x + (p << 8);
    int c = e & 3, o = (e >> 2) & 63;
    int i = (bx << 6) + (p << 2) + c;
    dst[(((bx << 4) + p) * 64 + o) * 4 + c] = src[o * DIN_ + i];
  }
}

__global__ __launch_bounds__(256) void proj_kernel(
    const float* __restrict__ x, float* __restrict__ ws) {
  __shared__ float tile[32][65];
  const int t0 = blockIdx.x << 5;
  const int b  = blockIdx.y;
  const int pj = blockIdx.z;
  const int spec = (t0 < ST_ || t0 >= ST_ + SEQ_) ? 1 : 0;
  const float4* W4 = reinterpret_cast<const float4*>(ws + WT4_OFF + (size_t)(pj*2 + spec) * (DIN_*64));
  const int lane = (int)threadIdx.x & 63;
  const int w = wuid();
  const float* xb = x + ((size_t)(b * T_ + t0 + (w << 3))) * DIN_;
  float acc[8] = {0.f,0.f,0.f,0.f,0.f,0.f,0.f,0.f};
  #pragma unroll 4
  for (int i4 = 0; i4 < 256; ++i4) {
    float4 wv = W4[(i4 << 6) + lane];
    #pragma unroll
    for (int r = 0; r < 8; ++r) {
      float4 xv = reinterpret_cast<const float4*>(xb + r * DIN_)[i4];
      acc[r] = fmaf(wv.x, xv.x, fmaf(wv.y, xv.y, fmaf(wv.z, xv.z, fmaf(wv.w, xv.w, acc[r]))));
    }
  }
  float outv[8];
  #pragma unroll
  for (int r = 0; r < 8; ++r) {
    float sq = acc[r] * acc[r];
    #pragma unroll
    for (int off = 32; off; off >>= 1) sq += __shfl_xor(sq, off, 64);
    float n = fmaxf(sqrtf(sq), 1e-12f);
    outv[r] = acc[r] / n;
  }
  const int trow = t0 + (w << 3);
  if (pj != 1) {
    float* dst = ws + (pj == 0 ? Q_OFF : V_OFF) + ((size_t)(b * T_ + trow)) * 64;
    #pragma unroll
    for (int r = 0; r < 8; ++r) dst[r * 64 + lane] = outv[r];
  } else {
    #pragma unroll
    for (int r = 0; r < 8; ++r) tile[(w << 3) + r][lane] = outv[r];
    __syncthreads();
    float* kt = ws + KT_OFF + (size_t)b * 16 * T_ * 4;
    #pragma unroll
    for (int p = 0; p < 8; ++p) {
      int e = (int)threadIdx.x + (p << 8);
      int c = e & 3, tt = (e >> 2) & 31, d4 = e >> 7;
      kt[((size_t)d4 * T_ + t0 + tt) * 4 + c] = tile[tt][(d4 << 2) + c];
    }
  }
}

__global__ __launch_bounds__(1024) void attn_kernel(
    const float* __restrict__ ws_c, const float* __restrict__ cope,
    const float* __restrict__ scalep, float* __restrict__ out) {
  __shared__ float li_s[8 * T_];
  __shared__ float pbuf[NW][8][32];
  __shared__ float totF[NW][8];
  __shared__ double suffD[NW][8];
  __shared__ double carryD[2][8];
  __shared__ float mlL[NW][8];
  __shared__ float wmax[NW][8];
  const int tid = (int)threadIdx.x;
  const int lane = tid & 63;
  const int w = wuid();
  const int t0 = ((int)(gridDim.x - 1 - blockIdx.x)) << 3;
  const int b  = blockIdx.y;
  const float* qrow = ws_c + Q_OFF + ((size_t)(b * T_ + t0)) * 64;
  const float* ktb  = ws_c + KT_OFF + (size_t)b * 16 * T_ * 4;
  const float* vb   = ws_c + V_OFF + ((size_t)b * T_) * 64;
  const float sc = scalep[0];
  if (tid < 8) carryD[0][tid] = 0.0;
  float lm[8];
  #pragma unroll
  for (int r = 0; r < 8; ++r) lm[r] = -INFINITY;
  for (int jt = 0; jt < 5; ++jt) {
    const int l = (jt << 10) + tid;
    if (l < T_) {
      float a[8] = {0,0,0,0,0,0,0,0};
      #pragma unroll 4
      for (int d4 = 0; d4 < 16; ++d4) {
        float c0 = cope[(d4 * 4 + 0) * T_ + l];
        float c1 = cope[(d4 * 4 + 1) * T_ + l];
        float c2 = cope[(d4 * 4 + 2) * T_ + l];
        float c3 = cope[(d4 * 4 + 3) * T_ + l];
        #pragma unroll
        for (int r = 0; r < 8; ++r) {
          float4 qq = *reinterpret_cast<const float4*>(qrow + r * 64 + (d4 << 2));
          a[r] = fmaf(c0, qq.x, fmaf(c1, qq.y, fmaf(c2, qq.z, fmaf(c3, qq.w, a[r]))));
        }
      }
      #pragma unroll
      for (int r = 0; r < 8; ++r) { li_s[r * T_ + l] = a[r]; lm[r] = fmaxf(lm[r], a[r]); }
    }
  }
  #pragma unroll
  for (int r = 0; r < 8; ++r) {
    #pragma unroll
    for (int off = 32; off; off >>= 1) lm[r] = fmaxf(lm[r], __shfl_xor(lm[r], off, 64));
  }
  if (lane == 0) {
    #pragma unroll
    for (int r = 0; r < 8; ++r) wmax[w][r] = lm[r];
  }
  __syncthreads();
  float mrow[8];
  #pragma unroll
  for (int r = 0; r < 8; ++r) {
    float mm = wmax[0][r];
    #pragma unroll
    for (int w2 = 1; w2 < NW; ++w2) mm = fmaxf(mm, wmax[w2][r]);
    mrow[r] = mm + fabsf(sc) + 1e-3f;
  }
  float acc[8]  = {0,0,0,0,0,0,0,0};
  float lsum[8] = {0,0,0,0,0,0,0,0};
  int par = 0;
  for (int jt = 4; jt >= 0; --jt) {
    const int s = (jt << 10) + tid;
    const bool sval = (s < T_);
    float lg[8] = {0,0,0,0,0,0,0,0};
    if (sval) {
      #pragma unroll 4
      for (int d4 = 0; d4 < 16; ++d4) {
        float4 kk = *reinterpret_cast<const float4*>(ktb + ((size_t)d4 * T_ + s) * 4);
        #pragma unroll
        for (int r = 0; r < 8; ++r) {
          float4 qq = *reinterpret_cast<const float4*>(qrow + r * 64 + (d4 << 2));
          lg[r] = fmaf(kk.x, qq.x, fmaf(kk.y, qq.y, fmaf(kk.z, qq.z, fmaf(kk.w, qq.w, lg[r]))));
        }
      }
    }
    float locsuf[8], gtot[8];
    #pragma unroll
    for (int r = 0; r < 8; ++r) {
      float g = sval ? 1.f / (1.f + __expf(-lg[r])) : 0.f;
      float xx = wave_iscan(g);
      float tt = __shfl(xx, 63, 64);
      locsuf[r] = tt - xx + g;
      gtot[r] = tt;
    }
    if (lane == 0) {
      #pragma unroll
      for (int r = 0; r < 8; ++r) totF[w][r] = gtot[r];
    }
    __syncthreads();
    if (tid < 128) {
      const int w2 = tid >> 3, r = tid & 7;
      float ssum = 0.f;
      for (int w3 = w2 + 1; w3 < NW; ++w3) ssum += totF[w3][r];
      suffD[w2][r] = carryD[par][r] + (double)ssum;
      if (w2 == 0) carryD[par ^ 1][r] = carryD[par][r] + (double)(ssum + totF[0][r]);
    }
    __syncthreads();
    par ^= 1;
    if ((jt << 10) > t0 + 7) continue;
    float p[8];
    #pragma unroll
    for (int r = 0; r < 8; ++r) {
      double posd = suffD[w][r] + (double)locsuf[r];
      if (posd > 4351.0) posd = 4351.0;
      int idx = (int)posd;
      float wf = (float)(posd - (double)idx);
      int idx2 = idx < 4351 ? idx + 1 : 4351;
      float lf = li_s[r * T_ + idx];
      float lc = li_s[r * T_ + idx2];
      float bias = fmaf(wf, lc - lf, lf);
      const int t = t0 + r;
      const bool valid = sval && (s <= t) && !((t >= ST_ + SEQ_) && (s < ST_));
      float score = valid ? fmaf(lg[r], sc, bias) : -INFINITY;
      p[r] = __expf(score - mrow[r]);
      lsum[r] += p[r];
    }
    const int sbase = (jt << 10) + (w << 6);
    if (sbase < T_) {
      #pragma unroll
      for (int pass = 0; pass < 2; ++pass) {
        if ((lane >> 5) == pass) {
          #pragma unroll
          for (int r = 0; r < 8; ++r) pbuf[w][r][lane & 31] = p[r];
        }
        const int s0 = sbase + (pass << 5);
        #pragma unroll 4
        for (int s4 = 0; s4 < 8; ++s4) {
          const int sb = s0 + (s4 << 2);
          float v0 = vb[(size_t)(sb + 0) * 64 + lane];
          float v1 = vb[(size_t)(sb + 1) * 64 + lane];
          float v2 = vb[(size_t)(sb + 2) * 64 + lane];
          float v3 = vb[(size_t)(sb + 3) * 64 + lane];
          #pragma unroll
          for (int r = 0; r < 8; ++r) {
            float4 pr = *reinterpret_cast<const float4*>(&pbuf[w][r][s4 << 2]);
            acc[r] = fmaf(pr.x, v0, fmaf(pr.y, v1, fmaf(pr.z, v2, fmaf(pr.w, v3, acc[r]))));
          }
        }
      }
    }
  }
  #pragma unroll
  for (int r = 0; r < 8; ++r) {
    #pragma unroll
    for (int off = 32; off; off >>= 1) lsum[r] += __shfl_xor(lsum[r], off, 64);
  }
  if (lane == 0) {
    #pragma unroll
    for (int r = 0; r < 8; ++r) mlL[w][r] = lsum[r];
  }
  float* pb = &pbuf[w][0][0];
  #pragma unroll
  for (int pass = 0; pass < 2; ++pass) {
    __syncthreads();
    #pragma unroll
    for (int rr = 0; rr < 4; ++rr) pb[rr * 64 + lane] = acc[pass * 4 + rr];
    __syncthreads();
    if (tid < 256) {
      const int rr = tid >> 6, d = tid & 63;
      const int r = pass * 4 + rr;
      float o = 0.f, L = 0.f;
      #pragma unroll
      for (int w2 = 0; w2 < NW; ++w2) {
        o += (&pbuf[w2][0][0])[rr * 64 + d];
        L += mlL[w2][r];
      }
      out[((size_t)(b * T_ + t0 + r)) * 64 + d] = o / L;
    }
  }
}

extern "C" void kernel_launch(void* const* d_in, const int* in_sizes, int n_in,
                              void* d_out, int out_size, void* d_ws, size_t ws_size,
                              hipStream_t stream) {
  const float* x    = (const float*)d_in[0];
  const float* Wq   = (const float*)d_in[1];
  const float* Wk   = (const float*)d_in[2];
  const float* Wv   = (const float*)d_in[3];
  const float* Wqs  = (const float*)d_in[4];
  const float* Wks  = (const float*)d_in[5];
  const float* Wvs  = (const float*)d_in[6];
  const float* cope = (const float*)d_in[7];
  const float* scl  = (const float*)d_in[8];
  float* outp = (float*)d_out;
  (void)in_sizes; (void)n_in; (void)out_size;

  if (ws_size >= NEED_NEW) {
    unsigned char* wb = (unsigned char*)d_ws;
    f16* whp = (f16*)(wb + OB_WH);
    f16* wlp = (f16*)(wb + OB_WL);
    f16* qh = (f16*)(wb + OB_QH);
    f16* kh = (f16*)(wb + OB_KH);
    f16* vt = (f16*)(wb + OB_VT);
    f16* cpt = (f16*)(wb + OB_CPT);
    hipLaunchKernelGGL(prep_kernel, dim3(148), dim3(256), 0, stream,
                       Wq, Wk, Wv, Wqs, Wks, Wvs, cope, whp, wlp, cpt);
    hipLaunchKernelGGL(projM_kernel, dim3(544), dim3(512), 0, stream,
                       x, whp, wlp, qh, kh, vt);
    hipLaunchKernelGGL(attnE_kernel, dim3(544), dim3(1024), 0, stream,
                       qh, kh, vt, cpt, scl, outp);
  } else {
    float* ws = (float*)d_ws;
    hipLaunchKernelGGL(wtrans_kernel, dim3(16, 6), dim3(256), 0, stream,
                       Wq, Wk, Wv, Wqs, Wks, Wvs, ws);
    hipLaunchKernelGGL(proj_kernel, dim3(136, 2, 3), dim3(256), 0, stream, x, ws);
    hipLaunchKernelGGL(attn_kernel, dim3(544, 2), dim3(1024), 0, stream, ws, cope, scl, outp);
  }
}

// Round 18
// 219.096 us; speedup vs baseline: 1.1449x; 1.0810x over previous
//
#include <hip/hip_runtime.h>
#include <math.h>

#define B_ 2
#define SEQ_ 4096
#define ST_ 128
#define T_ 4352
#define DIN_ 1024
#define NW 16
#define LMAX 3328
#define LPAD 3336
#define NSLICE 272
#define SLPAD 273
#define XPAD 1032

typedef _Float16 f16;
typedef __attribute__((ext_vector_type(8))) _Float16 f16x8;
typedef __attribute__((ext_vector_type(4))) float f32x4;

// ---- new-path ws byte offsets ----
#define OB_WH  0                 // 6*64*1024*2 = 786432
#define OB_WL  786432
#define OB_QH  1572864           // 8704*64*2 = 1114112
#define OB_KH  2686976
#define OB_VT  3801088
#define OB_CPT 4915200           // 3328*64*2 = 425984
#define NEED_NEW 5341184ull

// ---- old-path ws float offsets ----
#define WT4_OFF 0
#define Q_OFF   393216
#define KT_OFF  950272
#define V_OFF   1507328

__device__ __forceinline__ int wuid() {
  return __builtin_amdgcn_readfirstlane((int)(threadIdx.x >> 6));
}

template<int CTRL, int RM>
__device__ __forceinline__ float dppadd(float x) {
  int y = __builtin_amdgcn_update_dpp(0, __float_as_int(x), CTRL, RM, 0xf, true);
  return x + __int_as_float(y);
}
__device__ __forceinline__ float wave_iscan(float x) {
  x = dppadd<0x111, 0xf>(x);
  x = dppadd<0x112, 0xf>(x);
  x = dppadd<0x114, 0xf>(x);
  x = dppadd<0x118, 0xf>(x);
  x = dppadd<0x142, 0xa>(x);
  x = dppadd<0x143, 0xc>(x);
  return x;
}
__device__ __forceinline__ float p16scan(float x) {
  x = dppadd<0x111, 0xf>(x);
  x = dppadd<0x112, 0xf>(x);
  x = dppadd<0x114, 0xf>(x);
  x = dppadd<0x118, 0xf>(x);
  return x;
}
__device__ __forceinline__ float swz15(float x) {
  return __int_as_float(__builtin_amdgcn_ds_swizzle(__float_as_int(x), 0x1F0));
}

// ---------------- prep: W split (96 blocks) + cope transpose (52 blocks) ----------------
__global__ __launch_bounds__(256) void prep_kernel(
    const float* __restrict__ Wq,  const float* __restrict__ Wk,
    const float* __restrict__ Wv,  const float* __restrict__ Wqs,
    const float* __restrict__ Wks, const float* __restrict__ Wvs,
    const float* __restrict__ cope,
    f16* __restrict__ wh, f16* __restrict__ wl, f16* __restrict__ copeT) {
  __shared__ float t2[64][65];
  const int id = (int)blockIdx.x;
  const int tid = (int)threadIdx.x;
  if (id < 96) {
    const int m = id >> 4;
    const float* src = (m==0)?Wq:(m==1)?Wqs:(m==2)?Wk:(m==3)?Wks:(m==4)?Wv:Wvs;
    const int g0 = (id & 15) * 4096 + tid * 16;
    const float4* s4 = reinterpret_cast<const float4*>(src + g0);
    float4 v0 = s4[0], v1 = s4[1], v2 = s4[2], v3 = s4[3];
    f16x8 h0, h1, l0, l1;
    h0[0]=(f16)v0.x; h0[1]=(f16)v0.y; h0[2]=(f16)v0.z; h0[3]=(f16)v0.w;
    h0[4]=(f16)v1.x; h0[5]=(f16)v1.y; h0[6]=(f16)v1.z; h0[7]=(f16)v1.w;
    h1[0]=(f16)v2.x; h1[1]=(f16)v2.y; h1[2]=(f16)v2.z; h1[3]=(f16)v2.w;
    h1[4]=(f16)v3.x; h1[5]=(f16)v3.y; h1[6]=(f16)v3.z; h1[7]=(f16)v3.w;
    l0[0]=(f16)(v0.x-(float)h0[0]); l0[1]=(f16)(v0.y-(float)h0[1]);
    l0[2]=(f16)(v0.z-(float)h0[2]); l0[3]=(f16)(v0.w-(float)h0[3]);
    l0[4]=(f16)(v1.x-(float)h0[4]); l0[5]=(f16)(v1.y-(float)h0[5]);
    l0[6]=(f16)(v1.z-(float)h0[6]); l0[7]=(f16)(v1.w-(float)h0[7]);
    l1[0]=(f16)(v2.x-(float)h1[0]); l1[1]=(f16)(v2.y-(float)h1[1]);
    l1[2]=(f16)(v2.z-(float)h1[2]); l1[3]=(f16)(v2.w-(float)h1[3]);
    l1[4]=(f16)(v3.x-(float)h1[4]); l1[5]=(f16)(v3.y-(float)h1[5]);
    l1[6]=(f16)(v3.z-(float)h1[6]); l1[7]=(f16)(v3.w-(float)h1[7]);
    const size_t o = (size_t)m * 65536 + g0;
    *reinterpret_cast<f16x8*>(wh + o) = h0;
    *reinterpret_cast<f16x8*>(wh + o + 8) = h1;
    *reinterpret_cast<f16x8*>(wl + o) = l0;
    *reinterpret_cast<f16x8*>(wl + o + 8) = l1;
  } else {
    const int l0i = (id - 96) << 6;
    #pragma unroll
    for (int p = 0; p < 16; ++p) {
      int d = (p << 2) + (tid >> 6), c = tid & 63;
      t2[d][c] = cope[(size_t)d * T_ + l0i + c];
    }
    __syncthreads();
    #pragma unroll
    for (int p = 0; p < 16; ++p) {
      int l = (p << 2) + (tid >> 6), d = tid & 63;
      copeT[(size_t)(l0i + l) * 64 + d] = (f16)t2[d][l];
    }
  }
}

// ======== projM macros (3-pass; 8-wave K-split; LDS-staged x) ========
#define PM_MFMA(ACC, WHP, WLP) { \
  f16x8 bh_ = *reinterpret_cast<const f16x8*>((WHP) + (st << 5)); \
  f16x8 bl_ = *reinterpret_cast<const f16x8*>((WLP) + (st << 5)); \
  ACC = __builtin_amdgcn_mfma_f32_16x16x32_f16(xh_, bh_, ACC, 0, 0, 0); \
  ACC = __builtin_amdgcn_mfma_f32_16x16x32_f16(xl_, bh_, ACC, 0, 0, 0); \
  ACC = __builtin_amdgcn_mfma_f32_16x16x32_f16(xh_, bl_, ACC, 0, 0, 0); }

#define PM_RED(ACC, P) { \
  float s0_ = ACC[0]*ACC[0], s1_ = ACC[1]*ACC[1], s2_ = ACC[2]*ACC[2], s3_ = ACC[3]*ACC[3]; \
  s0_ += __shfl_xor(s0_, 1, 64); s1_ += __shfl_xor(s1_, 1, 64); \
  s2_ += __shfl_xor(s2_, 1, 64); s3_ += __shfl_xor(s3_, 1, 64); \
  s0_ += __shfl_xor(s0_, 2, 64); s1_ += __shfl_xor(s1_, 2, 64); \
  s2_ += __shfl_xor(s2_, 2, 64); s3_ += __shfl_xor(s3_, 2, 64); \
  s0_ += __shfl_xor(s0_, 4, 64); s1_ += __shfl_xor(s1_, 4, 64); \
  s2_ += __shfl_xor(s2_, 4, 64); s3_ += __shfl_xor(s3_, 4, 64); \
  s0_ += __shfl_xor(s0_, 8, 64); s1_ += __shfl_xor(s1_, 8, 64); \
  s2_ += __shfl_xor(s2_, 8, 64); s3_ += __shfl_xor(s3_, 8, 64); \
  if (qlo == 0) { \
    ssq[wn][P][(qhi << 2) + 0] = s0_; ssq[wn][P][(qhi << 2) + 1] = s1_; \
    ssq[wn][P][(qhi << 2) + 2] = s2_; ssq[wn][P][(qhi << 2) + 3] = s3_; } }

#define PM_QK1(ACC, P, HH, RG) { \
  float tt_ = ssq[0][P][(qhi << 2) + RG] + ssq[1][P][(qhi << 2) + RG] \
            + ssq[2][P][(qhi << 2) + RG] + ssq[3][P][(qhi << 2) + RG]; \
  float rn_ = 1.f / fmaxf(sqrtf(tt_), 1e-12f); \
  float v_ = ACC[RG] * rn_; \
  HH[(size_t)(bt0 + (qhi << 2) + RG) * 64 + (wn << 4) + qlo] = (f16)v_; }

#define PM_V1(ACC, P, RG) { \
  float tt_ = ssq[0][P][(qhi << 2) + RG] + ssq[1][P][(qhi << 2) + RG] \
            + ssq[2][P][(qhi << 2) + RG] + ssq[3][P][(qhi << 2) + RG]; \
  float rn_ = 1.f / fmaxf(sqrtf(tt_), 1e-12f); \
  vt[(size_t)(b * 64 + (wn << 4) + qlo) * T_ + t0 + (qhi << 2) + RG] = (f16)(ACC[RG] * rn_); }

// ---------------- MFMA projections + l2norm (8 waves, K-split, LDS-staged x) ----------------
__global__ __launch_bounds__(512, 4) void projM_kernel(
    const float* __restrict__ x,
    const f16* __restrict__ wh, const f16* __restrict__ wl,
    f16* __restrict__ qh, f16* __restrict__ kh, f16* __restrict__ vt) {
  __shared__ __align__(16) f16 xhL[16][XPAD];   // 33,024 B
  __shared__ __align__(16) f16 xlL[16][XPAD];   // 33,024 B
  __shared__ float ssq[4][3][16];
  __shared__ float part[4][64][12];
  const int tid = (int)threadIdx.x;
  const int lane = tid & 63;
  const int w = wuid();
  const int wn = w & 3;
  const int kh2 = w >> 2;
  const int qlo = lane & 15, qhi = lane >> 4;
  const int bt0 = (int)blockIdx.x << 4;
  const int b = bt0 / T_;
  const int t0 = bt0 - b * T_;
  const int spec = (t0 < ST_ || t0 >= ST_ + SEQ_) ? 1 : 0;

  // ---- phase A: load x tile once, convert to hi/lo f16, stage in LDS ----
  {
    const int xrow = tid >> 5;                 // 16 rows x 32 threads
    const int cbase = (tid & 31) << 3;         // 8-float chunks, coalesced
    const float* xs = x + (size_t)(bt0 + xrow) * DIN_;
    #pragma unroll
    for (int u = 0; u < 4; ++u) {
      const int col = cbase + (u << 8);
      float4 a_ = *reinterpret_cast<const float4*>(xs + col);
      float4 b_ = *reinterpret_cast<const float4*>(xs + col + 4);
      f16x8 hh, ll;
      hh[0]=(f16)a_.x; hh[1]=(f16)a_.y; hh[2]=(f16)a_.z; hh[3]=(f16)a_.w;
      hh[4]=(f16)b_.x; hh[5]=(f16)b_.y; hh[6]=(f16)b_.z; hh[7]=(f16)b_.w;
      ll[0]=(f16)(a_.x-(float)hh[0]); ll[1]=(f16)(a_.y-(float)hh[1]);
      ll[2]=(f16)(a_.z-(float)hh[2]); ll[3]=(f16)(a_.w-(float)hh[3]);
      ll[4]=(f16)(b_.x-(float)hh[4]); ll[5]=(f16)(b_.y-(float)hh[5]);
      ll[6]=(f16)(b_.z-(float)hh[6]); ll[7]=(f16)(b_.w-(float)hh[7]);
      *reinterpret_cast<f16x8*>(&xhL[xrow][col]) = hh;
      *reinterpret_cast<f16x8*>(&xlL[xrow][col]) = ll;
    }
  }
  __syncthreads();

  const int kof = kh2 << 9;
  const size_t wrow = (size_t)((wn << 4) + qlo) * 1024 + kof + (qhi << 3);
  const f16* wq  = wh + (size_t)(0 + spec) * 65536 + wrow;
  const f16* wqL = wl + (size_t)(0 + spec) * 65536 + wrow;
  const f16* wk  = wh + (size_t)(2 + spec) * 65536 + wrow;
  const f16* wkL = wl + (size_t)(2 + spec) * 65536 + wrow;
  const f16* wv  = wh + (size_t)(4 + spec) * 65536 + wrow;
  const f16* wvL = wl + (size_t)(4 + spec) * 65536 + wrow;
  const f16* xhr = &xhL[qlo][kof + (qhi << 3)];
  const f16* xlr = &xlL[qlo][kof + (qhi << 3)];

  f32x4 aq = {0.f,0.f,0.f,0.f}, ak = {0.f,0.f,0.f,0.f}, av = {0.f,0.f,0.f,0.f};

  #pragma unroll 4
  for (int st = 0; st < 16; ++st) {
    f16x8 xh_ = *reinterpret_cast<const f16x8*>(xhr + (st << 5));
    f16x8 xl_ = *reinterpret_cast<const f16x8*>(xlr + (st << 5));
    PM_MFMA(aq, wq, wqL)
    PM_MFMA(ak, wk, wkL)
    PM_MFMA(av, wv, wvL)
  }

  if (w >= 4) {
    float* p = &part[w - 4][lane][0];
    p[0] = aq[0]; p[1] = aq[1]; p[2]  = aq[2]; p[3]  = aq[3];
    p[4] = ak[0]; p[5] = ak[1]; p[6]  = ak[2]; p[7]  = ak[3];
    p[8] = av[0]; p[9] = av[1]; p[10] = av[2]; p[11] = av[3];
  }
  __syncthreads();
  if (w < 4) {
    const float* p = &part[w][lane][0];
    aq[0] += p[0]; aq[1] += p[1]; aq[2] += p[2];  aq[3] += p[3];
    ak[0] += p[4]; ak[1] += p[5]; ak[2] += p[6];  ak[3] += p[7];
    av[0] += p[8]; av[1] += p[9]; av[2] += p[10]; av[3] += p[11];
    PM_RED(aq, 0) PM_RED(ak, 1) PM_RED(av, 2)
  }
  __syncthreads();
  if (w < 4) {
    PM_QK1(aq, 0, qh, 0) PM_QK1(aq, 0, qh, 1)
    PM_QK1(aq, 0, qh, 2) PM_QK1(aq, 0, qh, 3)
    PM_QK1(ak, 1, kh, 0) PM_QK1(ak, 1, kh, 1)
    PM_QK1(ak, 1, kh, 2) PM_QK1(ak, 1, kh, 3)
    PM_V1(av, 2, 0) PM_V1(av, 2, 1) PM_V1(av, 2, 2) PM_V1(av, 2, 3)
  }
}

// ======== attnE macros (single-pass QK; PX split; in-LDS ss) ========
#define QKD(SF, NF) { \
  int sg_ = swb + (NF << 4) + qlo; \
  int scl_ = sg_ < T_ ? sg_ : T_ - 1; \
  const f16* krh_ = kh + bT64 + (size_t)scl_ * 64 + (qhi << 3); \
  f16x8 bh0_ = *reinterpret_cast<const f16x8*>(krh_); \
  f16x8 bh1_ = *reinterpret_cast<const f16x8*>(krh_ + 32); \
  f32x4 a_ = {0.f, 0.f, 0.f, 0.f}; \
  a_ = __builtin_amdgcn_mfma_f32_16x16x32_f16(aqh0, bh0_, a_, 0, 0, 0); \
  a_ = __builtin_amdgcn_mfma_f32_16x16x32_f16(aqh1, bh1_, a_, 0, 0, 0); \
  SF = a_; }

#define PXA(SF, RG, SSV, LF, LC, WF) { \
  float g_ = 1.f / (1.f + __expf(-SF[RG])); \
  float in_ = p16scan(g_); \
  float pos_ = SSV - in_ + g_; \
  pos_ = pos_ < 0.f ? 0.f : (pos_ > 3326.f ? 3326.f : pos_); \
  int idx_ = (int)pos_; \
  WF = pos_ - (float)idx_; \
  const f16* lrow_ = liL + ((qhi << 2) + RG) * LPAD + idx_; \
  LF = (float)lrow_[0]; LC = (float)lrow_[1]; }

#define PXB(SF, NF, RG, LF, LC, WF) { \
  int sg_ = swb + (NF << 4) + qlo; \
  float bias_ = fmaf(WF, LC - LF, LF); \
  int tl_ = t0 + (qhi << 2) + RG; \
  bool valid_ = (sg_ <= tl_) && !((tl_ >= ST_ + SEQ_) && (sg_ < ST_)); \
  float p_ = valid_ ? __expf(fmaf(SF[RG], sc, bias_) - mrw[RG]) : 0.f; \
  lsum[RG] += p_; \
  pst[((qhi << 2) + RG) * 40 + (NF << 4) + qlo] = (f16)p_; }

#define PVF(OA, NF) { \
  int d_ = (NF << 4) + qlo; \
  const f16* vr_ = vt + (size_t)(b * 64 + d_) * T_; \
  f16x8 v0_ = *reinterpret_cast<const f16x8*>(vr_ + sv0); \
  OA = __builtin_amdgcn_mfma_f32_16x16x32_f16(pa0, v0_, OA, 0, 0, 0); }

#define OST(OA, NF) { \
  ob[w * 1024 + ((qhi << 2) + 0) * 64 + (NF << 4) + qlo] = OA[0]; \
  ob[w * 1024 + ((qhi << 2) + 1) * 64 + (NF << 4) + qlo] = OA[1]; \
  ob[w * 1024 + ((qhi << 2) + 2) * 64 + (NF << 4) + qlo] = OA[2]; \
  ob[w * 1024 + ((qhi << 2) + 3) * 64 + (NF << 4) + qlo] = OA[3]; }

// ---------------- fused attention: gscan + barrier-free causal sweep ----------------
__global__ __launch_bounds__(1024, 4) void attnE_kernel(
    const f16* __restrict__ qh, const f16* __restrict__ kh,
    const f16* __restrict__ vt, const f16* __restrict__ cpt,
    const float* __restrict__ scalep, float* __restrict__ out) {
  __shared__ __align__(16) f16 liL[16 * LPAD];
  __shared__ __align__(16) f16 pstage[NW * 16 * 40];
  __shared__ float sl[16][SLPAD];
  __shared__ float totF[NW][16];
  __shared__ float rmxS[NW][16];

  const int tid = (int)threadIdx.x;
  const int lane = tid & 63;
  const int w = wuid();
  const int bt0 = ((int)(gridDim.x - 1 - blockIdx.x)) << 4;
  const int b = bt0 / T_;
  const int t0 = bt0 - b * T_;
  const float sc = scalep[0];
  const int qlo = lane & 15, qhi = lane >> 4;

  const f16* qrp = qh + (size_t)(bt0 + qlo) * 64 + (qhi << 3);
  f16x8 aqh0 = *reinterpret_cast<const f16x8*>(qrp);
  f16x8 aqh1 = *reinterpret_cast<const f16x8*>(qrp + 32);
  const size_t bT64 = (size_t)(b * T_) * 64;

  // ---- phase 1: li rows via MFMA into LDS + rowmax ----
  {
    f32x4 rm = {-1e30f, -1e30f, -1e30f, -1e30f};
    #pragma unroll 2
    for (int c = 0; c < 13; ++c) {
      const int lf = w * 208 + (c << 4);
      const f16* cr = cpt + (size_t)(lf + qlo) * 64 + (qhi << 3);
      f16x8 b0 = *reinterpret_cast<const f16x8*>(cr);
      f16x8 b1 = *reinterpret_cast<const f16x8*>(cr + 32);
      f32x4 a = {0.f, 0.f, 0.f, 0.f};
      a = __builtin_amdgcn_mfma_f32_16x16x32_f16(aqh0, b0, a, 0, 0, 0);
      a = __builtin_amdgcn_mfma_f32_16x16x32_f16(aqh1, b1, a, 0, 0, 0);
      f16 h0_ = (f16)a[0]; liL[((qhi << 2) + 0) * LPAD + lf + qlo] = h0_; rm[0] = fmaxf(rm[0], (float)h0_);
      f16 h1_ = (f16)a[1]; liL[((qhi << 2) + 1) * LPAD + lf + qlo] = h1_; rm[1] = fmaxf(rm[1], (float)h1_);
      f16 h2_ = (f16)a[2]; liL[((qhi << 2) + 2) * LPAD + lf + qlo] = h2_; rm[2] = fmaxf(rm[2], (float)h2_);
      f16 h3_ = (f16)a[3]; liL[((qhi << 2) + 3) * LPAD + lf + qlo] = h3_; rm[3] = fmaxf(rm[3], (float)h3_);
    }
    #pragma unroll
    for (int k = 1; k < 16; k <<= 1) {
      rm[0] = fmaxf(rm[0], __shfl_xor(rm[0], k, 64));
      rm[1] = fmaxf(rm[1], __shfl_xor(rm[1], k, 64));
      rm[2] = fmaxf(rm[2], __shfl_xor(rm[2], k, 64));
      rm[3] = fmaxf(rm[3], __shfl_xor(rm[3], k, 64));
    }
    if (qlo == 0) {
      rmxS[w][(qhi << 2) + 0] = rm[0];
      rmxS[w][(qhi << 2) + 1] = rm[1];
      rmxS[w][(qhi << 2) + 2] = rm[2];
      rmxS[w][(qhi << 2) + 3] = rm[3];
    }
  }

  // ---- phase 1.5: full QK gate slice sums (17 slices per wave) ----
  for (int i = 0; i < 17; ++i) {
    const int sli = w * 17 + i;
    const int sg = (sli << 4) + qlo;
    const f16* krh_ = kh + bT64 + (size_t)sg * 64 + (qhi << 3);
    f16x8 bh0 = *reinterpret_cast<const f16x8*>(krh_);
    f16x8 bh1 = *reinterpret_cast<const f16x8*>(krh_ + 32);
    f32x4 a = {0.f, 0.f, 0.f, 0.f};
    a = __builtin_amdgcn_mfma_f32_16x16x32_f16(aqh0, bh0, a, 0, 0, 0);
    a = __builtin_amdgcn_mfma_f32_16x16x32_f16(aqh1, bh1, a, 0, 0, 0);
    float g0 = 1.f / (1.f + __expf(-a[0])); float s0 = p16scan(g0);
    float g1 = 1.f / (1.f + __expf(-a[1])); float s1 = p16scan(g1);
    float g2 = 1.f / (1.f + __expf(-a[2])); float s2 = p16scan(g2);
    float g3 = 1.f / (1.f + __expf(-a[3])); float s3 = p16scan(g3);
    if (qlo == 15) {
      sl[(qhi << 2) + 0][sli] = s0;
      sl[(qhi << 2) + 1][sli] = s1;
      sl[(qhi << 2) + 2][sli] = s2;
      sl[(qhi << 2) + 3][sli] = s3;
    }
  }
  __syncthreads();

  // ---- phase 1.75: per-row fp64 suffix scan in LDS (wave w owns row w) ----
  {
    float* r = &sl[w][0];
    const int base = NSLICE - 1 - 5 * lane;
    double v0 = 0.0, v1 = 0.0, v2 = 0.0, v3 = 0.0, v4 = 0.0;
    double acc = 0.0;
    if (base - 0 >= 0) { acc += (double)r[base - 0]; } v0 = acc;
    if (base - 1 >= 0) { acc += (double)r[base - 1]; } v1 = acc;
    if (base - 2 >= 0) { acc += (double)r[base - 2]; } v2 = acc;
    if (base - 3 >= 0) { acc += (double)r[base - 3]; } v3 = acc;
    if (base - 4 >= 0) { acc += (double)r[base - 4]; } v4 = acc;
    double x = acc;
    #pragma unroll
    for (int off = 1; off < 64; off <<= 1) {
      double y = __shfl_up(x, off, 64);
      if (lane >= off) x += y;
    }
    const double offn = x - acc;
    if (base - 0 >= 0) r[base - 0] = (float)(v0 + offn);
    if (base - 1 >= 0) r[base - 1] = (float)(v1 + offn);
    if (base - 2 >= 0) r[base - 2] = (float)(v2 + offn);
    if (base - 3 >= 0) r[base - 3] = (float)(v3 + offn);
    if (base - 4 >= 0) r[base - 4] = (float)(v4 + offn);
  }

  f32x4 mrw;
  #pragma unroll
  for (int reg = 0; reg < 4; ++reg) {
    float mm = rmxS[0][(qhi << 2) + reg];
    #pragma unroll
    for (int w2 = 1; w2 < NW; ++w2) mm = fmaxf(mm, rmxS[w2][(qhi << 2) + reg]);
    mrw[reg] = mm + fabsf(sc) + 2e-3f;
  }
  __syncthreads();

  f16* pst = pstage + w * 640;

  f32x4 o0 = {0.f,0.f,0.f,0.f}, o1 = {0.f,0.f,0.f,0.f};
  f32x4 o2 = {0.f,0.f,0.f,0.f}, o3 = {0.f,0.f,0.f,0.f};
  f32x4 lsum = {0.f,0.f,0.f,0.f};

  const int jtmax = (t0 + 15) >> 9;
  for (int jt = jtmax; jt >= 0; --jt) {
    const int swb = (jt << 9) + (w << 5);
    f32x4 sf0, sf1;
    QKD(sf0, 0) QKD(sf1, 1)
    const int sbr = swb >> 4;
    const int sb0 = sbr < (NSLICE - 1) ? sbr : (NSLICE - 1);
    const int sb1 = (sbr + 1) < (NSLICE - 1) ? (sbr + 1) : (NSLICE - 1);
    float sA0 = sl[(qhi << 2) + 0][sb0];
    float sA1 = sl[(qhi << 2) + 1][sb0];
    float sA2 = sl[(qhi << 2) + 2][sb0];
    float sA3 = sl[(qhi << 2) + 3][sb0];
    float sB0 = sl[(qhi << 2) + 0][sb1];
    float sB1 = sl[(qhi << 2) + 1][sb1];
    float sB2 = sl[(qhi << 2) + 2][sb1];
    float sB3 = sl[(qhi << 2) + 3][sb1];
    float lf0, lc0, wf0, lf1, lc1, wf1, lf2, lc2, wf2, lf3, lc3, wf3;
    float lf4, lc4, wf4, lf5, lc5, wf5, lf6, lc6, wf6, lf7, lc7, wf7;
    PXA(sf0, 0, sA0, lf0, lc0, wf0) PXA(sf0, 1, sA1, lf1, lc1, wf1)
    PXA(sf0, 2, sA2, lf2, lc2, wf2) PXA(sf0, 3, sA3, lf3, lc3, wf3)
    PXA(sf1, 0, sB0, lf4, lc4, wf4) PXA(sf1, 1, sB1, lf5, lc5, wf5)
    PXA(sf1, 2, sB2, lf6, lc6, wf6) PXA(sf1, 3, sB3, lf7, lc7, wf7)
    PXB(sf0, 0, 0, lf0, lc0, wf0) PXB(sf0, 0, 1, lf1, lc1, wf1)
    PXB(sf0, 0, 2, lf2, lc2, wf2) PXB(sf0, 0, 3, lf3, lc3, wf3)
    PXB(sf1, 1, 0, lf4, lc4, wf4) PXB(sf1, 1, 1, lf5, lc5, wf5)
    PXB(sf1, 1, 2, lf6, lc6, wf6) PXB(sf1, 1, 3, lf7, lc7, wf7)
    {
      const f16* pr = pst + qlo * 40;
      f16x8 pa0 = *reinterpret_cast<const f16x8*>(pr + (qhi << 3));
      int sv0 = swb + (qhi << 3);
      sv0 = sv0 < T_ - 8 ? sv0 : T_ - 8;
      PVF(o0, 0) PVF(o1, 1) PVF(o2, 2) PVF(o3, 3)
    }
  }

  #pragma unroll
  for (int k = 1; k < 16; k <<= 1) {
    lsum[0] += __shfl_xor(lsum[0], k, 64);
    lsum[1] += __shfl_xor(lsum[1], k, 64);
    lsum[2] += __shfl_xor(lsum[2], k, 64);
    lsum[3] += __shfl_xor(lsum[3], k, 64);
  }
  __syncthreads();
  if (qlo == 0) {
    totF[w][(qhi << 2) + 0] = lsum[0];
    totF[w][(qhi << 2) + 1] = lsum[1];
    totF[w][(qhi << 2) + 2] = lsum[2];
    totF[w][(qhi << 2) + 3] = lsum[3];
  }
  float* ob = reinterpret_cast<float*>(liL);
  OST(o0, 0) OST(o1, 1) OST(o2, 2) OST(o3, 3)
  __syncthreads();
  {
    const int r = tid >> 6, d = tid & 63;
    float L = 0.f, o = 0.f;
    #pragma unroll
    for (int w2 = 0; w2 < NW; ++w2) {
      L += totF[w2][r];
      o += ob[w2 * 1024 + tid];
    }
    out[(size_t)(bt0 + r) * 64 + d] = o / L;
  }
}

// =================== OLD PATH (fallback, proven) ===================
__global__ __launch_bounds__(256) void wtrans_kernel(
    const float* __restrict__ Wq,  const float* __restrict__ Wk,
    const float* __restrict__ Wv,  const float* __restrict__ Wqs,
    const float* __restrict__ Wks, const float* __restrict__ Wvs,
    float* __restrict__ ws) {
  const int m = blockIdx.y;
  const float* src = (m==0)?Wq:(m==1)?Wqs:(m==2)?Wk:(m==3)?Wks:(m==4)?Wv:Wvs;
  float* dst = ws + (size_t)m * (DIN_*64);
  const int bx = blockIdx.x;
  #pragma unroll
  for (int p = 0; p < 16; ++p) {
    int e = (int)threadIdx.x + (p << 8);
    int c = e & 3, o = (e >> 2) & 63;
    int i = (bx << 6) + (p << 2) + c;
    dst[(((bx << 4) + p) * 64 + o) * 4 + c] = src[o * DIN_ + i];
  }
}

__global__ __launch_bounds__(256) void proj_kernel(
    const float* __restrict__ x, float* __restrict__ ws) {
  __shared__ float tile[32][65];
  const int t0 = blockIdx.x << 5;
  const int b  = blockIdx.y;
  const int pj = blockIdx.z;
  const int spec = (t0 < ST_ || t0 >= ST_ + SEQ_) ? 1 : 0;
  const float4* W4 = reinterpret_cast<const float4*>(ws + WT4_OFF + (size_t)(pj*2 + spec) * (DIN_*64));
  const int lane = (int)threadIdx.x & 63;
  const int w = wuid();
  const float* xb = x + ((size_t)(b * T_ + t0 + (w << 3))) * DIN_;
  float acc[8] = {0.f,0.f,0.f,0.f,0.f,0.f,0.f,0.f};
  #pragma unroll 4
  for (int i4 = 0; i4 < 256; ++i4) {
    float4 wv = W4[(i4 << 6) + lane];
    #pragma unroll
    for (int r = 0; r < 8; ++r) {
      float4 xv = reinterpret_cast<const float4*>(xb + r * DIN_)[i4];
      acc[r] = fmaf(wv.x, xv.x, fmaf(wv.y, xv.y, fmaf(wv.z, xv.z, fmaf(wv.w, xv.w, acc[r]))));
    }
  }
  float outv[8];
  #pragma unroll
  for (int r = 0; r < 8; ++r) {
    float sq = acc[r] * acc[r];
    #pragma unroll
    for (int off = 32; off; off >>= 1) sq += __shfl_xor(sq, off, 64);
    float n = fmaxf(sqrtf(sq), 1e-12f);
    outv[r] = acc[r] / n;
  }
  const int trow = t0 + (w << 3);
  if (pj != 1) {
    float* dst = ws + (pj == 0 ? Q_OFF : V_OFF) + ((size_t)(b * T_ + trow)) * 64;
    #pragma unroll
    for (int r = 0; r < 8; ++r) dst[r * 64 + lane] = outv[r];
  } else {
    #pragma unroll
    for (int r = 0; r < 8; ++r) tile[(w << 3) + r][lane] = outv[r];
    __syncthreads();
    float* kt = ws + KT_OFF + (size_t)b * 16 * T_ * 4;
    #pragma unroll
    for (int p = 0; p < 8; ++p) {
      int e = (int)threadIdx.x + (p << 8);
      int c = e & 3, tt = (e >> 2) & 31, d4 = e >> 7;
      kt[((size_t)d4 * T_ + t0 + tt) * 4 + c] = tile[tt][(d4 << 2) + c];
    }
  }
}

__global__ __launch_bounds__(1024) void attn_kernel(
    const float* __restrict__ ws_c, const float* __restrict__ cope,
    const float* __restrict__ scalep, float* __restrict__ out) {
  __shared__ float li_s[8 * T_];
  __shared__ float pbuf[NW][8][32];
  __shared__ float totF[NW][8];
  __shared__ double suffD[NW][8];
  __shared__ double carryD[2][8];
  __shared__ float mlL[NW][8];
  __shared__ float wmax[NW][8];
  const int tid = (int)threadIdx.x;
  const int lane = tid & 63;
  const int w = wuid();
  const int t0 = ((int)(gridDim.x - 1 - blockIdx.x)) << 3;
  const int b  = blockIdx.y;
  const float* qrow = ws_c + Q_OFF + ((size_t)(b * T_ + t0)) * 64;
  const float* ktb  = ws_c + KT_OFF + (size_t)b * 16 * T_ * 4;
  const float* vb   = ws_c + V_OFF + ((size_t)b * T_) * 64;
  const float sc = scalep[0];
  if (tid < 8) carryD[0][tid] = 0.0;
  float lm[8];
  #pragma unroll
  for (int r = 0; r < 8; ++r) lm[r] = -INFINITY;
  for (int jt = 0; jt < 5; ++jt) {
    const int l = (jt << 10) + tid;
    if (l < T_) {
      float a[8] = {0,0,0,0,0,0,0,0};
      #pragma unroll 4
      for (int d4 = 0; d4 < 16; ++d4) {
        float c0 = cope[(d4 * 4 + 0) * T_ + l];
        float c1 = cope[(d4 * 4 + 1) * T_ + l];
        float c2 = cope[(d4 * 4 + 2) * T_ + l];
        float c3 = cope[(d4 * 4 + 3) * T_ + l];
        #pragma unroll
        for (int r = 0; r < 8; ++r) {
          float4 qq = *reinterpret_cast<const float4*>(qrow + r * 64 + (d4 << 2));
          a[r] = fmaf(c0, qq.x, fmaf(c1, qq.y, fmaf(c2, qq.z, fmaf(c3, qq.w, a[r]))));
        }
      }
      #pragma unroll
      for (int r = 0; r < 8; ++r) { li_s[r * T_ + l] = a[r]; lm[r] = fmaxf(lm[r], a[r]); }
    }
  }
  #pragma unroll
  for (int r = 0; r < 8; ++r) {
    #pragma unroll
    for (int off = 32; off; off >>= 1) lm[r] = fmaxf(lm[r], __shfl_xor(lm[r], off, 64));
  }
  if (lane == 0) {
    #pragma unroll
    for (int r = 0; r < 8; ++r) wmax[w][r] = lm[r];
  }
  __syncthreads();
  float mrow[8];
  #pragma unroll
  for (int r = 0; r < 8; ++r) {
    float mm = wmax[0][r];
    #pragma unroll
    for (int w2 = 1; w2 < NW; ++w2) mm = fmaxf(mm, wmax[w2][r]);
    mrow[r] = mm + fabsf(sc) + 1e-3f;
  }
  float acc[8]  = {0,0,0,0,0,0,0,0};
  float lsum[8] = {0,0,0,0,0,0,0,0};
  int par = 0;
  for (int jt = 4; jt >= 0; --jt) {
    const int s = (jt << 10) + tid;
    const bool sval = (s < T_);
    float lg[8] = {0,0,0,0,0,0,0,0};
    if (sval) {
      #pragma unroll 4
      for (int d4 = 0; d4 < 16; ++d4) {
        float4 kk = *reinterpret_cast<const float4*>(ktb + ((size_t)d4 * T_ + s) * 4);
        #pragma unroll
        for (int r = 0; r < 8; ++r) {
          float4 qq = *reinterpret_cast<const float4*>(qrow + r * 64 + (d4 << 2));
          lg[r] = fmaf(kk.x, qq.x, fmaf(kk.y, qq.y, fmaf(kk.z, qq.z, fmaf(kk.w, qq.w, lg[r]))));
        }
      }
    }
    float locsuf[8], gtot[8];
    #pragma unroll
    for (int r = 0; r < 8; ++r) {
      float g = sval ? 1.f / (1.f + __expf(-lg[r])) : 0.f;
      float xx = wave_iscan(g);
      float tt = __shfl(xx, 63, 64);
      locsuf[r] = tt - xx + g;
      gtot[r] = tt;
    }
    if (lane == 0) {
      #pragma unroll
      for (int r = 0; r < 8; ++r) totF[w][r] = gtot[r];
    }
    __syncthreads();
    if (tid < 128) {
      const int w2 = tid >> 3, r = tid & 7;
      float ssum = 0.f;
      for (int w3 = w2 + 1; w3 < NW; ++w3) ssum += totF[w3][r];
      suffD[w2][r] = carryD[par][r] + (double)ssum;
      if (w2 == 0) carryD[par ^ 1][r] = carryD[par][r] + (double)(ssum + totF[0][r]);
    }
    __syncthreads();
    par ^= 1;
    if ((jt << 10) > t0 + 7) continue;
    float p[8];
    #pragma unroll
    for (int r = 0; r < 8; ++r) {
      double posd = suffD[w][r] + (double)locsuf[r];
      if (posd > 4351.0) posd = 4351.0;
      int idx = (int)posd;
      float wf = (float)(posd - (double)idx);
      int idx2 = idx < 4351 ? idx + 1 : 4351;
      float lf = li_s[r * T_ + idx];
      float lc = li_s[r * T_ + idx2];
      float bias = fmaf(wf, lc - lf, lf);
      const int t = t0 + r;
      const bool valid = sval && (s <= t) && !((t >= ST_ + SEQ_) && (s < ST_));
      float score = valid ? fmaf(lg[r], sc, bias) : -INFINITY;
      p[r] = __expf(score - mrow[r]);
      lsum[r] += p[r];
    }
    const int sbase = (jt << 10) + (w << 6);
    if (sbase < T_) {
      #pragma unroll
      for (int pass = 0; pass < 2; ++pass) {
        if ((lane >> 5) == pass) {
          #pragma unroll
          for (int r = 0; r < 8; ++r) pbuf[w][r][lane & 31] = p[r];
        }
        const int s0 = sbase + (pass << 5);
        #pragma unroll 4
        for (int s4 = 0; s4 < 8; ++s4) {
          const int sb = s0 + (s4 << 2);
          float v0 = vb[(size_t)(sb + 0) * 64 + lane];
          float v1 = vb[(size_t)(sb + 1) * 64 + lane];
          float v2 = vb[(size_t)(sb + 2) * 64 + lane];
          float v3 = vb[(size_t)(sb + 3) * 64 + lane];
          #pragma unroll
          for (int r = 0; r < 8; ++r) {
            float4 pr = *reinterpret_cast<const float4*>(&pbuf[w][r][s4 << 2]);
            acc[r] = fmaf(pr.x, v0, fmaf(pr.y, v1, fmaf(pr.z, v2, fmaf(pr.w, v3, acc[r]))));
          }
        }
      }
    }
  }
  #pragma unroll
  for (int r = 0; r < 8; ++r) {
    #pragma unroll
    for (int off = 32; off; off >>= 1) lsum[r] += __shfl_xor(lsum[r], off, 64);
  }
  if (lane == 0) {
    #pragma unroll
    for (int r = 0; r < 8; ++r) mlL[w][r] = lsum[r];
  }
  float* pb = &pbuf[w][0][0];
  #pragma unroll
  for (int pass = 0; pass < 2; ++pass) {
    __syncthreads();
    #pragma unroll
    for (int rr = 0; rr < 4; ++rr) pb[rr * 64 + lane] = acc[pass * 4 + rr];
    __syncthreads();
    if (tid < 256) {
      const int rr = tid >> 6, d = tid & 63;
      const int r = pass * 4 + rr;
      float o = 0.f, L = 0.f;
      #pragma unroll
      for (int w2 = 0; w2 < NW; ++w2) {
        o += (&pbuf[w2][0][0])[rr * 64 + d];
        L += mlL[w2][r];
      }
      out[((size_t)(b * T_ + t0 + r)) * 64 + d] = o / L;
    }
  }
}

extern "C" void kernel_launch(void* const* d_in, const int* in_sizes, int n_in,
                              void* d_out, int out_size, void* d_ws, size_t ws_size,
                              hipStream_t stream) {
  const float* x    = (const float*)d_in[0];
  const float* Wq   = (const float*)d_in[1];
  const float* Wk   = (const float*)d_in[2];
  const float* Wv   = (const float*)d_in[3];
  const float* Wqs  = (const float*)d_in[4];
  const float* Wks  = (const float*)d_in[5];
  const float* Wvs  = (const float*)d_in[6];
  const float* cope = (const float*)d_in[7];
  const float* scl  = (const float*)d_in[8];
  float* outp = (float*)d_out;
  (void)in_sizes; (void)n_in; (void)out_size;

  if (ws_size >= NEED_NEW) {
    unsigned char* wb = (unsigned char*)d_ws;
    f16* whp = (f16*)(wb + OB_WH);
    f16* wlp = (f16*)(wb + OB_WL);
    f16* qh = (f16*)(wb + OB_QH);
    f16* kh = (f16*)(wb + OB_KH);
    f16* vt = (f16*)(wb + OB_VT);
    f16* cpt = (f16*)(wb + OB_CPT);
    hipLaunchKernelGGL(prep_kernel, dim3(148), dim3(256), 0, stream,
                       Wq, Wk, Wv, Wqs, Wks, Wvs, cope, whp, wlp, cpt);
    hipLaunchKernelGGL(projM_kernel, dim3(544), dim3(512), 0, stream,
                       x, whp, wlp, qh, kh, vt);
    hipLaunchKernelGGL(attnE_kernel, dim3(544), dim3(1024), 0, stream,
                       qh, kh, vt, cpt, scl, outp);
  } else {
    float* ws = (float*)d_ws;
    hipLaunchKernelGGL(wtrans_kernel, dim3(16, 6), dim3(256), 0, stream,
                       Wq, Wk, Wv, Wqs, Wks, Wvs, ws);
    hipLaunchKernelGGL(proj_kernel, dim3(136, 2, 3), dim3(256), 0, stream, x, ws);
    hipLaunchKernelGGL(attn_kernel, dim3(544, 2), dim3(1024), 0, stream, ws, cope, scl, outp);
  }
}